// Round 9
// baseline (444.532 us; speedup 1.0000x reference)
//
#include <hip/hip_runtime.h>

#define SLOPE 0.01f
#define BN_EPS 1e-5f

typedef __attribute__((ext_vector_type(8))) short short8;
typedef __attribute__((ext_vector_type(4))) float f32x4;

static constexpr int D1 = 32, H1 = 96, W1_ = 96;
static constexpr int HW1 = H1 * W1_, DHW1 = D1 * HW1;        // 294912
static constexpr int D0 = 16, H0 = 48, W0 = 48;
static constexpr int HW0 = H0 * W0, DHW0 = D0 * HW0;         // 36864

static constexpr int FP_PLPTS = 98 * 98;            // fine padded plane pts
static constexpr int CP_PLPTS = 50 * 50;            // coarse padded plane pts
static constexpr int FP_ELEMS = 33 * FP_PLPTS * 64; // fine padded buffer elems

__device__ __forceinline__ short f2bf(float f) {
    unsigned u = __builtin_bit_cast(unsigned, f);
    unsigned r = (u + 0x7fffu + ((u >> 16) & 1u)) >> 16;
    return (short)r;
}
__device__ __forceinline__ float bf2f(short s) {
    unsigned u = ((unsigned)(unsigned short)s) << 16;
    return __builtin_bit_cast(float, u);
}
__device__ __forceinline__ int pidx_fine(int s) {
    int z = s / HW1; int r = s - z * HW1; int y = r / W1_; int x = r - y * W1_;
    return z * FP_PLPTS + (y + 1) * 98 + (x + 1);
}
__device__ __forceinline__ int pidx_coarse(int s) {
    int z = s / HW0; int r = s - z * HW0; int y = r / W0; int x = r - y * W0;
    return z * CP_PLPTS + (y + 1) * 50 + (x + 1);
}
__device__ __forceinline__ void gload16(const void* g, void* l) {
    __builtin_amdgcn_global_load_lds(
        (const __attribute__((address_space(1))) void*)g,
        (__attribute__((address_space(3))) void*)l, 16, 0, 0);
}

// ---------------------------------------------------------------------------
__global__ __launch_bounds__(256)
void to_cl_pad128(const float* __restrict__ in, short* __restrict__ out)
{
    __shared__ float t[64][65];
    const int s0 = blockIdx.x * 64, c0 = blockIdx.y * 64;
    const int tid = threadIdx.x;
    {
        const int cpr = tid >> 2, ch = tid & 3;
        const float4* ip = (const float4*)(in + (size_t)(c0 + cpr) * DHW0 + s0 + ch * 16);
        #pragma unroll
        for (int i = 0; i < 4; ++i) {
            float4 v = ip[i]; int sb = ch * 16 + i * 4;
            t[sb][cpr] = v.x; t[sb + 1][cpr] = v.y; t[sb + 2][cpr] = v.z; t[sb + 3][cpr] = v.w;
        }
    }
    __syncthreads();
    {
        const int spr = tid >> 2, cc = (tid & 3) * 16;
        short8 o0, o1;
        #pragma unroll
        for (int q = 0; q < 8; ++q) { o0[q] = f2bf(t[spr][cc + q]); o1[q] = f2bf(t[spr][cc + 8 + q]); }
        const int p = pidx_coarse(s0 + spr);
        short* op = out + (size_t)p * 128 + c0 + cc;
        *(short8*)op = o0;
        *(short8*)(op + 8) = o1;
    }
}

__global__ __launch_bounds__(256)
void to_cl_bf16(const float* __restrict__ in, short* __restrict__ out, int S)
{
    __shared__ float t[64][65];
    const int s0 = blockIdx.x * 64;
    const int tid = threadIdx.x;
    {
        const int cpr = tid >> 2, ch = tid & 3;
        const float4* ip = (const float4*)(in + (size_t)cpr * S + s0 + ch * 16);
        #pragma unroll
        for (int i = 0; i < 4; ++i) {
            float4 v = ip[i]; int sb = ch * 16 + i * 4;
            t[sb][cpr] = v.x; t[sb + 1][cpr] = v.y; t[sb + 2][cpr] = v.z; t[sb + 3][cpr] = v.w;
        }
    }
    __syncthreads();
    {
        const int spr = tid >> 2, cc = (tid & 3) * 16;
        short8 o0, o1;
        #pragma unroll
        for (int q = 0; q < 8; ++q) { o0[q] = f2bf(t[spr][cc + q]); o1[q] = f2bf(t[spr][cc + 8 + q]); }
        short* op = out + (size_t)(s0 + spr) * 64 + cc;
        *(short8*)op = o0;
        *(short8*)(op + 8) = o1;
    }
}

// repack (unscaled) wt_t + wt_1: [o][ci][t] fp32 -> [t][o][ci] bf16
__global__ __launch_bounds__(256)
void prep_all(const float* __restrict__ wt, const float* __restrict__ w1,
              short* dt, short* d1)
{
    int i = blockIdx.x * 256 + threadIdx.x;
    if (i < 221184) {
        int t = i / 8192; int r = i % 8192; int o = r >> 7; int ci = r & 127;
        dt[i] = f2bf(wt[(size_t)(o * 128 + ci) * 27 + t]);
        return;
    }
    i -= 221184;
    if (i < 36864) {
        int t = i / 4096; int r = i & 4095; int o = r >> 6; int ci = r & 63;
        d1[i] = f2bf(w1[(size_t)(o * 64 + ci) * 9 + t]);
    }
}

__global__ void finalize_stats(const float* __restrict__ stats, const float* __restrict__ g,
                               const float* __restrict__ b, float invN, float* __restrict__ aff)
{
    int c = threadIdx.x;
    float m = stats[c] * invN;
    float var = stats[64 + c] * invN - m * m;
    float rstd = rsqrtf(var + BN_EPS);
    float sc = g[c] * rstd;
    aff[c] = sc;
    aff[64 + c] = b[c] - m * sc;
}

__global__ __launch_bounds__(256)
void final_out(const short* __restrict__ in, float* __restrict__ out, const float* __restrict__ aff)
{
    __shared__ float t[64][65];
    const int s0 = blockIdx.x * 64;
    const int tid = threadIdx.x;
    {
        const int spr = tid >> 2, ch = tid & 3;
        const short8* ip = (const short8*)(in + (size_t)(s0 + spr) * 64 + ch * 16);
        short8 v0 = ip[0], v1 = ip[1];
        #pragma unroll
        for (int q = 0; q < 8; ++q) { int c = ch * 16 + q;     t[spr][c] = bf2f(v0[q]) * aff[c] + aff[64 + c]; }
        #pragma unroll
        for (int q = 0; q < 8; ++q) { int c = ch * 16 + 8 + q; t[spr][c] = bf2f(v1[q]) * aff[c] + aff[64 + c]; }
    }
    __syncthreads();
    {
        const int c = tid >> 2, sc = (tid & 3) * 16;
        #pragma unroll
        for (int i = 0; i < 4; ++i) {
            float4 w;
            w.x = t[sc + 4 * i][c]; w.y = t[sc + 4 * i + 1][c];
            w.z = t[sc + 4 * i + 2][c]; w.w = t[sc + 4 * i + 3][c];
            *(float4*)(out + (size_t)c * DHW1 + s0 + sc + 4 * i) = w;
        }
    }
}

// ---------------------------------------------------------------------------
// merged zeroing: PadA/PadB halo edges + trash plane, X0/Y0 same, stats+biases
__global__ __launch_bounds__(256)
void zero_misc(short* __restrict__ PadA, short* __restrict__ PadB,
               short* __restrict__ X0, short* __restrict__ Y0, float* __restrict__ stats)
{
    const short8 z8 = {0, 0, 0, 0, 0, 0, 0, 0};
    int i = blockIdx.x * 256 + threadIdx.x;
    constexpr int T_F = 33 * 3104 + 76832;
    constexpr int T_X = 17 * 3136 + 40000;
    constexpr int T_Y = 17 * 1568 + 20000;
    constexpr int TOT = 2 * T_F + T_X + T_Y + 432;   // 432 f4 = stats/affs/biases
    if (i >= TOT) return;

    auto fine_off = [](int q) -> size_t {
        if (q < 33 * 3104) {
            int pl = q / 3104, e = q % 3104, p = e >> 3, c = e & 7;
            int y, x;
            if (p < 98) { y = 0; x = p; }
            else if (p < 196) { y = 97; x = p - 98; }
            else { int q2 = p - 196; y = 1 + (q2 >> 1); x = (q2 & 1) ? 97 : 0; }
            return ((size_t)pl * FP_PLPTS + y * 98 + x) * 64 + c * 8;
        }
        int q2 = q - 33 * 3104;
        return (size_t)32 * FP_PLPTS * 64 + (size_t)q2 * 8;
    };
    auto co_off = [](int q, int CPR) -> size_t {
        const int EPP = 196 * CPR;
        if (q < 17 * EPP) {
            int pl = q / EPP, e = q % EPP, p = e / CPR, c = e % CPR;
            int y, x;
            if (p < 50) { y = 0; x = p; }
            else if (p < 100) { y = 49; x = p - 50; }
            else { int r = p - 100; y = 1 + (r >> 1); x = (r & 1) ? 49 : 0; }
            return ((size_t)pl * CP_PLPTS + y * 50 + x) * (CPR * 8) + c * 8;
        }
        int q2 = q - 17 * EPP;
        return (size_t)16 * CP_PLPTS * (CPR * 8) + (size_t)q2 * 8;
    };

    if (i < T_F) { *(short8*)(PadA + fine_off(i)) = z8; return; } i -= T_F;
    if (i < T_F) { *(short8*)(PadB + fine_off(i)) = z8; return; } i -= T_F;
    if (i < T_X) { *(short8*)(X0 + co_off(i, 16)) = z8; return; } i -= T_X;
    if (i < T_Y) { *(short8*)(Y0 + co_off(i, 8)) = z8; return; } i -= T_Y;
    float4 zf = {0.f, 0.f, 0.f, 0.f};
    *(float4*)((char*)stats + (size_t)i * 16) = zf;
}

// ---------------------------------------------------------------------------
// Per-stage BN-fold prep for fine convs: scale w by sc[ci] -> [t][o][ci] bf16,
// bias[o] = sum w*sh[ci], fill consumed buffer's halos+trash with hv=-sh/sc.
template<int KSZ>
__global__ __launch_bounds__(256)
void prep_fine(const float* __restrict__ w, const float* __restrict__ aff,
               short* __restrict__ dst, float* __restrict__ bias,
               short* __restrict__ buf)
{
    __shared__ float red[256];
    constexpr int NSC = KSZ * 4096 / 256;
    int b = blockIdx.x;
    if (b < NSC) {
        int i = b * 256 + threadIdx.x;
        int t = i / 4096; int r = i & 4095; int o = r >> 6; int ci = r & 63;
        dst[i] = f2bf(w[(size_t)(o * 64 + ci) * KSZ + t] * aff[ci]);
        return;
    }
    b -= NSC;
    if (b < 64) {                       // bias[o]
        int o = b;
        float p = 0.f;
        for (int i = threadIdx.x; i < 64 * KSZ; i += 256) {
            int ci = i / KSZ, t = i % KSZ;
            p += w[(size_t)(o * 64 + ci) * KSZ + t] * aff[64 + ci];
        }
        red[threadIdx.x] = p;
        __syncthreads();
        #pragma unroll
        for (int off = 128; off > 0; off >>= 1) {
            if (threadIdx.x < off) red[threadIdx.x] += red[threadIdx.x + off];
            __syncthreads();
        }
        if (threadIdx.x == 0) bias[o] = red[0];
        return;
    }
    b -= 64;
    int q = b * 256 + threadIdx.x;
    constexpr int T_F = 33 * 3104 + 76832;
    if (q >= T_F) return;
    size_t off; int cb;
    if (q < 33 * 3104) {
        int pl = q / 3104, e = q % 3104, p = e >> 3; cb = e & 7;
        int y, x;
        if (p < 98) { y = 0; x = p; }
        else if (p < 196) { y = 97; x = p - 98; }
        else { int r = p - 196; y = 1 + (r >> 1); x = (r & 1) ? 97 : 0; }
        off = ((size_t)pl * FP_PLPTS + y * 98 + x) * 64 + cb * 8;
    } else {
        int q2 = q - 33 * 3104; cb = q2 & 7;
        off = (size_t)32 * FP_PLPTS * 64 + (size_t)q2 * 8;
    }
    short8 hv;
    #pragma unroll
    for (int k = 0; k < 8; ++k) { int c = cb * 8 + k; hv[k] = f2bf(-aff[64 + c] / aff[c]); }
    *(short8*)(buf + off) = hv;
}

// BN-fold prep for tconv: scale w_up by sc0, per-class bias, fill Y0 halos.
__global__ __launch_bounds__(256)
void prep_up(const float* __restrict__ wup, const float* __restrict__ aff,
             short* __restrict__ dst, float* __restrict__ bias_up,
             short* __restrict__ Y0)
{
    __shared__ float red[64];
    int b = blockIdx.x;
    if (b < 432) {                      // scale 27*64*64
        int i = b * 256 + threadIdx.x;
        int t = i / 4096; int r = i & 4095; int o = r >> 6; int ci = r & 63;
        dst[i] = f2bf(wup[(size_t)(o * 64 + ci) * 27 + t] * aff[ci]);
        return;
    }
    b -= 432;
    if (b < 512) {                      // bias[cls][o]
        int cls = b >> 6, o = b & 63;
        int pz = (cls >> 2) & 1, py = (cls >> 1) & 1, px = cls & 1;
        int ci = threadIdx.x;
        if (ci < 64) {
            float p = 0.f;
            for (int a = 0; a <= pz; ++a) { int kd = pz ? 2 * a : 1;
                for (int b2 = 0; b2 <= py; ++b2) { int kh = py ? 2 * b2 : 1;
                    for (int c2 = 0; c2 <= px; ++c2) { int kw = px ? 2 * c2 : 1;
                        p += wup[(size_t)(o * 64 + ci) * 27 + kd * 9 + kh * 3 + kw];
                    } } }
            red[ci] = p * aff[64 + ci];
        }
        __syncthreads();
        if (threadIdx.x == 0) {
            float s = 0.f;
            for (int k = 0; k < 64; ++k) s += red[k];
            bias_up[cls * 64 + o] = s;
        }
        return;
    }
    b -= 512;
    int q = b * 256 + threadIdx.x;
    constexpr int T_Y = 17 * 1568 + 20000;
    if (q >= T_Y) return;
    size_t off; int cb;
    if (q < 17 * 1568) {
        int pl = q / 1568, e = q % 1568, p = e >> 3; cb = e & 7;
        int y, x;
        if (p < 50) { y = 0; x = p; }
        else if (p < 100) { y = 49; x = p - 50; }
        else { int r = p - 100; y = 1 + (r >> 1); x = (r & 1) ? 49 : 0; }
        off = ((size_t)pl * CP_PLPTS + y * 50 + x) * 64 + cb * 8;
    } else {
        int q2 = q - 17 * 1568; cb = q2 & 7;
        off = (size_t)16 * CP_PLPTS * 64 + (size_t)q2 * 8;
    }
    short8 hv;
    #pragma unroll
    for (int k = 0; k < 8; ++k) { int c = cb * 8 + k; hv[k] = f2bf(-aff[64 + c] / aff[c]); }
    *(short8*)(Y0 + off) = hv;
}

// ---------------------------------------------------------------------------
// Stage-A conv (CIN=128, coarse): R6-proven 2-phase counted-vmcnt kernel, MG=1.
template<int MG, int CIN, int KD, int KH, int KW, int PD, int PH, int PW,
         int GD, int GH, int GW, int OUTMODE, bool STATS>
__global__ __launch_bounds__(256, 2)
void convmm5(const short* __restrict__ A, const short* __restrict__ Wt,
             short* __restrict__ Out, float* __restrict__ stats)
{
    constexpr int MR   = 64 * MG;
    constexpr int KSZ  = KD * KH * KW;
    constexpr int PPW  = GW + 2;
    constexpr int PLP  = (GH + 2) * PPW;
    constexpr int HWg  = GH * GW;
    constexpr int CPR  = CIN / 8;
    constexpr int L2C  = (CIN == 64) ? 3 : 4;
    constexpr int RPI  = 64 / CPR;
    constexpr int ASZ  = MR * CIN * 2;
    constexpr int BSZ  = 64 * CIN * 2;
    constexpr int API  = ASZ / 4096;
    constexpr int BPI  = BSZ / 4096;
    constexpr int KCN  = CIN / 32;
    constexpr int S_IF = API + BPI;

    __shared__ char smem[2 * ASZ + 2 * BSZ];

    const int tid = threadIdx.x, lane = tid & 63, wave = tid >> 6;
    const int rl = lane & 15, kg = lane >> 4;

    const int nwg = gridDim.x;
    const int bid = blockIdx.x;
    const int bswz = (nwg & 7) ? bid : ((bid & 7) * (nwg >> 3) + (bid >> 3));
    const int row0 = bswz * MR;

    int zA[API], yxA[API], cofA[API];
    #pragma unroll
    for (int i = 0; i < API; ++i) {
        const int gi = wave * API + i;
        const int r = gi * RPI + (lane >> L2C);
        const int s = row0 + r;
        const int z = s / HWg; const int rm = s - z * HWg;
        const int y = rm / GW; const int x = rm - y * GW;
        zA[i] = z;
        yxA[i] = (y + 1) * PPW + (x + 1);
        cofA[i] = ((lane & (CPR - 1)) ^ (r & 7)) * 8;
    }
    int rB[BPI], cofB[BPI];
    #pragma unroll
    for (int i = 0; i < BPI; ++i) {
        const int gi = wave * BPI + i;
        const int r = gi * RPI + (lane >> L2C);
        rB[i] = r;
        cofB[i] = ((lane & (CPR - 1)) ^ (r & 7)) * 8;
    }

    auto stageA = [&](int bsel, int kd, int kh, int kw) {
        const int dyx = (kh - PH) * PPW + (kw - PW);
        #pragma unroll
        for (int i = 0; i < API; ++i) {
            int zp = zA[i] + (kd - PD);
            int pl = ((unsigned)zp < (unsigned)GD) ? zp : GD;
            const short* src = A + ((size_t)pl * PLP + yxA[i] + dyx) * CIN + cofA[i];
            void* dst = smem + bsel * ASZ + (wave * API + i) * 1024;
            gload16(src, dst);
        }
    };
    auto stageB = [&](int bsel, int t) {
        const short* wt = Wt + (size_t)t * 64 * CIN;
        #pragma unroll
        for (int i = 0; i < BPI; ++i) {
            const short* src = wt + rB[i] * CIN + cofB[i];
            void* dst = smem + 2 * ASZ + bsel * BSZ + (wave * BPI + i) * 1024;
            gload16(src, dst);
        }
    };

    f32x4 acc[MG][4];
    #pragma unroll
    for (int mg = 0; mg < MG; ++mg)
        #pragma unroll
        for (int ng = 0; ng < 4; ++ng)
            acc[mg][ng] = (f32x4){0.f, 0.f, 0.f, 0.f};

    auto comp = [&](int bsel) {
        const short* ab = (const short*)(smem + bsel * ASZ);
        const short* bb = (const short*)(smem + 2 * ASZ + bsel * BSZ);
        #pragma unroll
        for (int kc = 0; kc < KCN; ++kc) {
            short8 av[MG], bv[4];
            #pragma unroll
            for (int mg = 0; mg < MG; ++mg) {
                const int r = wave * (16 * MG) + mg * 16 + rl;
                const int c = (kc * 4 + kg) ^ (r & 7);
                av[mg] = *(const short8*)(ab + r * CIN + c * 8);
            }
            #pragma unroll
            for (int ng = 0; ng < 4; ++ng) {
                const int r = ng * 16 + rl;
                const int c = (kc * 4 + kg) ^ (r & 7);
                bv[ng] = *(const short8*)(bb + r * CIN + c * 8);
            }
            __builtin_amdgcn_s_setprio(1);
            #pragma unroll
            for (int mg = 0; mg < MG; ++mg)
                #pragma unroll
                for (int ng = 0; ng < 4; ++ng)
                    acc[mg][ng] = __builtin_amdgcn_mfma_f32_16x16x32_bf16(av[mg], bv[ng], acc[mg][ng], 0, 0, 0);
            __builtin_amdgcn_s_setprio(0);
        }
    };

    stageA(0, 0, 0, 0);
    stageB(0, 0);

    #pragma unroll
    for (int t = 0; t < KSZ; ++t) {
        const int cur = t & 1;
        if (t + 1 < KSZ) {
            const int t1 = t + 1;
            const int kd = t1 / (KH * KW), rm = t1 % (KH * KW);
            stageA(cur ^ 1, kd, rm / KW, rm % KW);
            stageB(cur ^ 1, t1);
            asm volatile("s_waitcnt vmcnt(%0)" :: "i"(S_IF) : "memory");
        } else {
            asm volatile("s_waitcnt vmcnt(0)" ::: "memory");
        }
        __builtin_amdgcn_s_barrier();
        __builtin_amdgcn_sched_barrier(0);
        comp(cur);
        asm volatile("s_waitcnt lgkmcnt(0)" ::: "memory");
        __builtin_amdgcn_sched_barrier(0);
        __builtin_amdgcn_s_barrier();
    }

    short (*tile)[64] = (short(*)[64])smem;
    float* red = (float*)(smem + 2 * ASZ);

    #pragma unroll
    for (int mg = 0; mg < MG; ++mg)
        #pragma unroll
        for (int ng = 0; ng < 4; ++ng)
            #pragma unroll
            for (int j = 0; j < 4; ++j) {
                float v = acc[mg][ng][j];
                if (STATS) v = (v >= 0.f) ? v : SLOPE * v;
                tile[wave * (16 * MG) + mg * 16 + kg * 4 + j][ng * 16 + rl] = f2bf(v);
            }
    __syncthreads();

    #pragma unroll
    for (int i = 0; i < MR / 32; ++i) {
        const int chunk = i * 256 + tid;
        const int r = chunk >> 3, cc = (chunk & 7) * 8;
        const int s = row0 + r;
        size_t o;
        if (OUTMODE == 0)      o = (size_t)s * 64 + cc;
        else if (OUTMODE == 1) o = (size_t)pidx_fine(s) * 64 + cc;
        else                   o = (size_t)pidx_coarse(s) * 64 + cc;
        *(short8*)(Out + o) = *(const short8*)&tile[r][cc];
    }

    if (STATS) {
        float s1 = 0.f, s2 = 0.f;
        const int col = tid & 63, rg = tid >> 6;
        #pragma unroll 4
        for (int r = rg * (MR / 4); r < (rg + 1) * (MR / 4); ++r) {
            float v = bf2f(tile[r][col]); s1 += v; s2 += v * v;
        }
        red[rg * 64 + col] = s1;
        red[256 + rg * 64 + col] = s2;
        __syncthreads();
        if (tid < 64) {
            float a = red[tid] + red[64 + tid] + red[128 + tid] + red[192 + tid];
            float b = red[256 + tid] + red[320 + tid] + red[384 + tid] + red[448 + tid];
            atomicAdd(&stats[tid], a);
            atomicAdd(&stats[64 + tid], b);
        }
    }
}

// ---------------------------------------------------------------------------
// Fine convs (C/D/E): R8 structure + B in registers (per-tap dbuf, 1-tap
// prefetch distance) + bias-initialized accumulator (BN fold). A-only LDS
// (2x26624=52KB -> 3 blocks/CU). Barriers 2/group; counted vmcnt per tap.
template<int KD, int KH, int PD, int PH, int OUTMODE>
__global__ __launch_bounds__(128, 1)
void convmm8(const short* __restrict__ A, const short* __restrict__ Wt,
             const float* __restrict__ bias,
             short* __restrict__ Out, float* __restrict__ stats)
{
    constexpr int NG = KD * KH, KSZ = NG * 3;
    constexpr int PLP = FP_PLPTS;
    constexpr int ABYTES = 208 * 128;     // 26624
    __shared__ __align__(16) char smem[2 * ABYTES];   // 53248 -> 3 blocks/CU

    const int tid = threadIdx.x, lane = tid & 63, wave = tid >> 6;  // wave 0..1
    const int rl = lane & 15, kg = lane >> 4;

    const int nwg = gridDim.x, bid = blockIdx.x;
    const int bswz = (bid & 7) * (nwg >> 3) + (bid >> 3);
    const int s0 = bswz * 192;
    const int z0 = s0 / HW1;
    const int y0 = (s0 - z0 * HW1) / 96;

    const int ptl = lane >> 3;
    const int csl = (lane & 7) ^ ptl;

    auto stageA = [&](int bsel, int g) {
        const int kd = g / KH, kh = g % KH;
        const int zp = z0 + kd - PD;
        const int pl = ((unsigned)zp < 32u) ? zp : 32;   // trash plane (hv or zero)
        const int ys = y0 + kh - PH;
        const size_t base = (size_t)pl * PLP + (size_t)(ys + 1) * 98;
        #pragma unroll
        for (int i = 0; i < 13; ++i) {
            const int ii = wave * 13 + i;
            const short* src = A + (base + ii * 8 + ptl) * 64 + csl * 8;
            gload16(src, smem + bsel * ABYTES + ii * 1024);
        }
    };
    auto loadB = [&](short8 (&dst)[8], int t) {
        const short* wt = Wt + (size_t)t * 4096;
        #pragma unroll
        for (int kc = 0; kc < 2; ++kc)
            #pragma unroll
            for (int ng = 0; ng < 4; ++ng)
                dst[kc * 4 + ng] = *(const short8*)(wt + (ng * 16 + rl) * 64 + (kc * 4 + kg) * 8);
    };

    float bc[4];
    #pragma unroll
    for (int ng = 0; ng < 4; ++ng) bc[ng] = bias[ng * 16 + rl];
    f32x4 acc[6][4];
    #pragma unroll
    for (int mg = 0; mg < 6; ++mg)
        #pragma unroll
        for (int ng = 0; ng < 4; ++ng)
            acc[mg][ng] = (f32x4){bc[ng], bc[ng], bc[ng], bc[ng]};

    const int jb = wave * 98 + rl;

    auto compTap = [&](const short8 (&bv)[8], const char* ab, int kw) {
        #pragma unroll
        for (int kc = 0; kc < 2; ++kc) {
            short8 av[6];
            #pragma unroll
            for (int mg = 0; mg < 6; ++mg) {
                const int j = jb + mg * 16 + kw;
                av[mg] = *(const short8*)(ab + j * 128 + (((kc * 4 + kg) ^ (j & 7)) << 4));
            }
            __builtin_amdgcn_s_setprio(1);
            #pragma unroll
            for (int mg = 0; mg < 6; ++mg)
                #pragma unroll
                for (int ng = 0; ng < 4; ++ng)
                    acc[mg][ng] = __builtin_amdgcn_mfma_f32_16x16x32_bf16(av[mg], bv[kc * 4 + ng], acc[mg][ng], 0, 0, 0);
            __builtin_amdgcn_s_setprio(0);
        }
    };

    short8 brA[8], brB[8];
    stageA(0, 0);
    loadB(brA, 0);

    #pragma unroll
    for (int g = 0; g < NG; ++g) {
        if (g + 1 < NG) stageA((g + 1) & 1, g + 1);
        #pragma unroll
        for (int kw = 0; kw < 3; ++kw) {
            const int t = 3 * g + kw;
            if (t + 1 < KSZ) {
                if ((t + 1) & 1) loadB(brB, t + 1); else loadB(brA, t + 1);
            }
            // counted waits: allow {A-stage(g+1):13, B(t+1):8} in flight
            const bool moreA = (g + 1 < NG), moreB = (t + 1 < KSZ);
            if (moreA && moreB)      asm volatile("s_waitcnt vmcnt(21)" ::: "memory");
            else if (moreB)          asm volatile("s_waitcnt vmcnt(8)" ::: "memory");
            else                     asm volatile("s_waitcnt vmcnt(0)" ::: "memory");
            if (kw == 0) __builtin_amdgcn_s_barrier();   // A buffer ready (all waves)
            __builtin_amdgcn_sched_barrier(0);
            const char* ab = smem + (g & 1) * ABYTES;
            if (t & 1) compTap(brB, ab, kw); else compTap(brA, ab, kw);
        }
        asm volatile("s_waitcnt lgkmcnt(0)" ::: "memory");   // my LDS reads done
        __builtin_amdgcn_sched_barrier(0);
        __builtin_amdgcn_s_barrier();                        // safe to overwrite
    }

    short (*tile)[64] = (short(*)[64])smem;
    float* red = (float*)(smem + 192 * 64 * 2);

    #pragma unroll
    for (int mg = 0; mg < 6; ++mg)
        #pragma unroll
        for (int ng = 0; ng < 4; ++ng)
            #pragma unroll
            for (int j = 0; j < 4; ++j) {
                float v = acc[mg][ng][j];
                v = (v >= 0.f) ? v : SLOPE * v;
                tile[wave * 96 + mg * 16 + kg * 4 + j][ng * 16 + rl] = f2bf(v);
            }
    __syncthreads();

    #pragma unroll
    for (int i = 0; i < 12; ++i) {
        const int chunk = i * 128 + tid;
        const int r = chunk >> 3, cc = (chunk & 7) * 8;
        const int s = s0 + r;
        size_t o;
        if (OUTMODE == 0) o = (size_t)s * 64 + cc;
        else              o = (size_t)pidx_fine(s) * 64 + cc;
        *(short8*)(Out + o) = *(const short8*)&tile[r][cc];
    }

    {
        float s1 = 0.f, s2 = 0.f;
        const int col = tid & 63, rg = tid >> 6;
        #pragma unroll 4
        for (int r = rg * 96; r < rg * 96 + 96; ++r) {
            float v = bf2f(tile[r][col]); s1 += v; s2 += v * v;
        }
        red[rg * 64 + col] = s1;
        red[128 + rg * 64 + col] = s2;
        __syncthreads();
        if (tid < 64) {
            atomicAdd(&stats[tid], red[tid] + red[64 + tid]);
            atomicAdd(&stats[64 + tid], red[128 + tid] + red[192 + tid]);
        }
    }
}

// ---------------------------------------------------------------------------
// Transposed conv by output-parity class (R6-proven) + per-class BN-fold bias.
__global__ __launch_bounds__(256, 2)
void tconv_cls(const short* __restrict__ Y, const short* __restrict__ Wt,
               const float* __restrict__ bias_up,
               const short* __restrict__ SK, short* __restrict__ Out)
{
    const int cls = blockIdx.y;
    const int pz = (cls >> 2) & 1, py = (cls >> 1) & 1, px = cls & 1;
    const int tid = threadIdx.x, lane = tid & 63, wave = tid >> 6;
    const int rl = lane & 15, kg = lane >> 4;
    const int row0 = blockIdx.x * 256;

    int zin0[4], zin1[4];
    #pragma unroll
    for (int mg = 0; mg < 4; ++mg) {
        int s = row0 + wave * 64 + mg * 16 + rl;
        int zc = s / HW0; int r = s - zc * HW0; int yc = r / W0; int xc = r - yc * W0;
        int ib = ((yc + 1) * 50 + (xc + 1)) * 64 + kg * 8;
        zin0[mg] = zc * (CP_PLPTS * 64) + ib;
        zin1[mg] = ((zc + 1 < 16) ? zc + 1 : 16) * (CP_PLPTS * 64) + ib;
    }
    const int boff = rl * 64 + kg * 8;

    float bc[4];
    #pragma unroll
    for (int ng = 0; ng < 4; ++ng) bc[ng] = bias_up[cls * 64 + ng * 16 + rl];
    f32x4 acc[4][4];
    #pragma unroll
    for (int mg = 0; mg < 4; ++mg)
        #pragma unroll
        for (int ng = 0; ng < 4; ++ng)
            acc[mg][ng] = (f32x4){bc[ng], bc[ng], bc[ng], bc[ng]};

    for (int a = 0; a <= pz; ++a) {
        const int kd = pz ? 2 * a : 1;
        for (int b = 0; b <= py; ++b) {
            const int kh = py ? 2 * b : 1;
            for (int c = 0; c <= px; ++c) {
                const int kw = px ? 2 * c : 1;
                const int t = kd * 9 + kh * 3 + kw;
                const int dlt = (b * 50 + c) * 64;
                int ao[4];
                #pragma unroll
                for (int mg = 0; mg < 4; ++mg)
                    ao[mg] = (a ? zin1[mg] : zin0[mg]) + dlt;
                #pragma unroll
                for (int kc = 0; kc < 2; ++kc) {
                    short8 av[4], bv[4];
                    #pragma unroll
                    for (int mg = 0; mg < 4; ++mg)
                        av[mg] = *(const short8*)(Y + ao[mg] + kc * 32);
                    #pragma unroll
                    for (int ng = 0; ng < 4; ++ng)
                        bv[ng] = *(const short8*)(Wt + (t * 64 + ng * 16) * 64 + boff + kc * 32);
                    #pragma unroll
                    for (int mg = 0; mg < 4; ++mg)
                        #pragma unroll
                        for (int ng = 0; ng < 4; ++ng)
                            acc[mg][ng] = __builtin_amdgcn_mfma_f32_16x16x32_bf16(av[mg], bv[ng], acc[mg][ng], 0, 0, 0);
                }
            }
        }
    }

    __shared__ short tile[256][72];
    #pragma unroll
    for (int mg = 0; mg < 4; ++mg)
        #pragma unroll
        for (int ng = 0; ng < 4; ++ng)
            #pragma unroll
            for (int j = 0; j < 4; ++j)
                tile[wave * 64 + mg * 16 + kg * 4 + j][ng * 16 + rl] = f2bf(acc[mg][ng][j]);
    __syncthreads();

    #pragma unroll
    for (int i = 0; i < 8; ++i) {
        int chunk = i * 256 + tid;
        int r = chunk >> 3, cc = (chunk & 7) * 8;
        int sl = row0 + r;
        int zc = sl / HW0; int rr = sl - zc * HW0; int yc = rr / W0; int xc = rr - yc * W0;
        int z = 2 * zc + pz, y = 2 * yc + py, x = 2 * xc + px;
        size_t so = (size_t)((z * H1 + y) * W1_ + x) * 64 + cc;
        size_t po = (size_t)(z * FP_PLPTS + (y + 1) * 98 + (x + 1)) * 64 + cc;
        short8 v = *(const short8*)&tile[r][cc];
        short8 skv = *(const short8*)(SK + so);
        short8 o;
        #pragma unroll
        for (int q = 0; q < 8; ++q) o[q] = f2bf(bf2f(v[q]) + bf2f(skv[q]));
        *(short8*)(Out + po) = o;
    }
}

// ---------------------------------------------------------------------------
extern "C" void kernel_launch(void* const* d_in, const int* in_sizes, int n_in,
                              void* d_out, int out_size, void* d_ws, size_t ws_size,
                              hipStream_t stream)
{
    const float* x       = (const float*)d_in[0];
    const float* skip    = (const float*)d_in[1];
    const float* w_trans = (const float*)d_in[2];
    const float* g_t     = (const float*)d_in[3];
    const float* b_t     = (const float*)d_in[4];
    const float* w_up    = (const float*)d_in[5];
    const float* w1      = (const float*)d_in[6];
    const float* g1      = (const float*)d_in[7];
    const float* b1      = (const float*)d_in[8];
    const float* w2      = (const float*)d_in[9];
    const float* g2      = (const float*)d_in[10];
    const float* b2      = (const float*)d_in[11];
    const float* w3      = (const float*)d_in[12];
    const float* g3      = (const float*)d_in[13];
    const float* b3      = (const float*)d_in[14];
    float* out = (float*)d_out;

    char* ws = (char*)d_ws;
    short* PadA = (short*)ws;
    short* PadB = (short*)(ws + (size_t)FP_ELEMS * 2);
    float* stats = (float*)(ws + (size_t)FP_ELEMS * 4);

    float* st0 = stats;       float* af0 = stats + 512;
    float* st1 = stats + 128; float* af1 = stats + 512 + 128;
    float* st2 = stats + 256; float* af2 = stats + 512 + 256;
    float* st3 = stats + 384; float* af3 = stats + 512 + 384;
    float* bias2 = stats + 1024;
    float* bias3 = stats + 1088;
    float* bias_up = stats + 1152;   // 8*64
    float* bias_z  = stats + 1664;   // zeros (for conv C)

    char* ob = (char*)d_out;
    short* X0  = (short*)ob;
    short* Y0  = (short*)(ob + 10880000);
    short* SKb = (short*)(ob + 16320000);
    short* wt_t  = (short*)(ob + 54068736);
    short* wt_up = wt_t + 221184;
    short* wt_1  = wt_up + 110592;
    short* wt_2  = wt_1 + 36864;
    short* wt_3  = wt_2 + 36864;

    // merged zeroing (halo edges + trash planes + stats/biases)
    constexpr int T_F = 33 * 3104 + 76832;
    constexpr int T_X = 17 * 3136 + 40000;
    constexpr int T_Y = 17 * 1568 + 20000;
    zero_misc<<<(2 * T_F + T_X + T_Y + 432 + 255) / 256, 256, 0, stream>>>(PadA, PadB, X0, Y0, stats);

    // unscaled repacks (stage A weights + conv-C weights)
    prep_all<<<(221184 + 36864 + 255) / 256, 256, 0, stream>>>(w_trans, w1, wt_t, wt_1);

    // input transposes
    to_cl_pad128<<<dim3(DHW0 / 64, 2), 256, 0, stream>>>(x, X0);
    to_cl_bf16<<<DHW1 / 64, 256, 0, stream>>>(skip, SKb, DHW1);

    // stage A: subm 3x3x3 CIN=128 coarse -> Y0pad (raw lrelu) + stats
    convmm5<1, 128, 3, 3, 3, 1, 1, 1, 16, 48, 48, 2, true>
        <<<DHW0 / 64, 256, 0, stream>>>(X0, wt_t, Y0, st0);
    finalize_stats<<<1, 64, 0, stream>>>(st0, g_t, b_t, 1.f / DHW0, af0);
    // fold af0: scaled w_up + per-class bias + Y0 halo fill (hv0)
    prep_up<<<432 + 512 + (T_Y + 255) / 256, 256, 0, stream>>>(w_up, af0, wt_up, bias_up, Y0);

    // stage B: transposed conv by parity class (+bias) + skip -> PadA
    tconv_cls<<<dim3(DHW0 / 256, 8), 256, 0, stream>>>(Y0, wt_up, bias_up, SKb, PadA);

    // stage C: conv (1,3,3) pad (0,1,1) -> PadB raw + stats (no fold on input)
    convmm8<1, 3, 0, 1, 1>
        <<<DHW1 / 192, 128, 0, stream>>>(PadA, wt_1, bias_z, PadB, st1);
    finalize_stats<<<1, 64, 0, stream>>>(st1, g1, b1, 1.f / DHW1, af1);
    // fold af1: scaled w2 + bias2 + PadB halo fill (hv1)
    prep_fine<9><<<144 + 64 + (T_F + 255) / 256, 256, 0, stream>>>(w2, af1, wt_2, bias2, PadB);

    // stage D: conv (3,1,3) pad (1,0,1) -> PadA raw + stats
    convmm8<3, 1, 1, 0, 1>
        <<<DHW1 / 192, 128, 0, stream>>>(PadB, wt_2, bias2, PadA, st2);
    finalize_stats<<<1, 64, 0, stream>>>(st2, g2, b2, 1.f / DHW1, af2);
    // fold af2: scaled w3 + bias3 + PadA halo fill (hv2)
    prep_fine<27><<<432 + 64 + (T_F + 255) / 256, 256, 0, stream>>>(w3, af2, wt_3, bias3, PadA);

    // stage E: conv (3,3,3) pad 1 -> PadB COMPACT raw + stats
    convmm8<3, 3, 1, 1, 0>
        <<<DHW1 / 192, 128, 0, stream>>>(PadA, wt_3, bias3, PadB, st3);
    finalize_stats<<<1, 64, 0, stream>>>(st3, g3, b3, 1.f / DHW1, af3);

    // final: aff3 + transpose to NCDHW fp32
    final_out<<<DHW1 / 64, 256, 0, stream>>>(PadB, out, af3);
}

// Round 10
// 393.762 us; speedup vs baseline: 1.1289x; 1.1289x over previous
//
#include <hip/hip_runtime.h>

#define SLOPE 0.01f
#define BN_EPS 1e-5f

typedef __attribute__((ext_vector_type(8))) short short8;
typedef __attribute__((ext_vector_type(4))) float f32x4;

static constexpr int D1 = 32, H1 = 96, W1_ = 96;
static constexpr int HW1 = H1 * W1_, DHW1 = D1 * HW1;        // 294912
static constexpr int D0 = 16, H0 = 48, W0 = 48;
static constexpr int HW0 = H0 * W0, DHW0 = D0 * HW0;         // 36864

static constexpr int FP_PLPTS = 98 * 98;
static constexpr int CP_PLPTS = 50 * 50;
static constexpr int FP_ELEMS = 33 * FP_PLPTS * 64;

__device__ __forceinline__ short f2bf(float f) {
    unsigned u = __builtin_bit_cast(unsigned, f);
    unsigned r = (u + 0x7fffu + ((u >> 16) & 1u)) >> 16;
    return (short)r;
}
__device__ __forceinline__ float bf2f(short s) {
    unsigned u = ((unsigned)(unsigned short)s) << 16;
    return __builtin_bit_cast(float, u);
}
__device__ __forceinline__ int pidx_fine(int s) {
    int z = s / HW1; int r = s - z * HW1; int y = r / W1_; int x = r - y * W1_;
    return z * FP_PLPTS + (y + 1) * 98 + (x + 1);
}
__device__ __forceinline__ int pidx_coarse(int s) {
    int z = s / HW0; int r = s - z * HW0; int y = r / W0; int x = r - y * W0;
    return z * CP_PLPTS + (y + 1) * 50 + (x + 1);
}
__device__ __forceinline__ void gload16(const void* g, void* l) {
    __builtin_amdgcn_global_load_lds(
        (const __attribute__((address_space(1))) void*)g,
        (__attribute__((address_space(3))) void*)l, 16, 0, 0);
}

// ---------------------------------------------------------------------------
__global__ __launch_bounds__(256)
void to_cl_pad128(const float* __restrict__ in, short* __restrict__ out)
{
    __shared__ float t[64][65];
    const int s0 = blockIdx.x * 64, c0 = blockIdx.y * 64;
    const int tid = threadIdx.x;
    {
        const int cpr = tid >> 2, ch = tid & 3;
        const float4* ip = (const float4*)(in + (size_t)(c0 + cpr) * DHW0 + s0 + ch * 16);
        #pragma unroll
        for (int i = 0; i < 4; ++i) {
            float4 v = ip[i]; int sb = ch * 16 + i * 4;
            t[sb][cpr] = v.x; t[sb + 1][cpr] = v.y; t[sb + 2][cpr] = v.z; t[sb + 3][cpr] = v.w;
        }
    }
    __syncthreads();
    {
        const int spr = tid >> 2, cc = (tid & 3) * 16;
        short8 o0, o1;
        #pragma unroll
        for (int q = 0; q < 8; ++q) { o0[q] = f2bf(t[spr][cc + q]); o1[q] = f2bf(t[spr][cc + 8 + q]); }
        const int p = pidx_coarse(s0 + spr);
        short* op = out + (size_t)p * 128 + c0 + cc;
        *(short8*)op = o0;
        *(short8*)(op + 8) = o1;
    }
}

__global__ __launch_bounds__(256)
void to_cl_bf16(const float* __restrict__ in, short* __restrict__ out, int S)
{
    __shared__ float t[64][65];
    const int s0 = blockIdx.x * 64;
    const int tid = threadIdx.x;
    {
        const int cpr = tid >> 2, ch = tid & 3;
        const float4* ip = (const float4*)(in + (size_t)cpr * S + s0 + ch * 16);
        #pragma unroll
        for (int i = 0; i < 4; ++i) {
            float4 v = ip[i]; int sb = ch * 16 + i * 4;
            t[sb][cpr] = v.x; t[sb + 1][cpr] = v.y; t[sb + 2][cpr] = v.z; t[sb + 3][cpr] = v.w;
        }
    }
    __syncthreads();
    {
        const int spr = tid >> 2, cc = (tid & 3) * 16;
        short8 o0, o1;
        #pragma unroll
        for (int q = 0; q < 8; ++q) { o0[q] = f2bf(t[spr][cc + q]); o1[q] = f2bf(t[spr][cc + 8 + q]); }
        short* op = out + (size_t)(s0 + spr) * 64 + cc;
        *(short8*)op = o0;
        *(short8*)(op + 8) = o1;
    }
}

// repack (unscaled) wt_t + wt_1: [o][ci][t] fp32 -> [t][o][ci] bf16
__global__ __launch_bounds__(256)
void prep_all(const float* __restrict__ wt, const float* __restrict__ w1,
              short* dt, short* d1)
{
    int i = blockIdx.x * 256 + threadIdx.x;
    if (i < 221184) {
        int t = i / 8192; int r = i % 8192; int o = r >> 7; int ci = r & 127;
        dt[i] = f2bf(wt[(size_t)(o * 128 + ci) * 27 + t]);
        return;
    }
    i -= 221184;
    if (i < 36864) {
        int t = i / 4096; int r = i & 4095; int o = r >> 6; int ci = r & 63;
        d1[i] = f2bf(w1[(size_t)(o * 64 + ci) * 9 + t]);
    }
}

__global__ void finalize_stats(const float* __restrict__ stats, const float* __restrict__ g,
                               const float* __restrict__ b, float invN, float* __restrict__ aff)
{
    int c = threadIdx.x;
    float m = stats[c] * invN;
    float var = stats[64 + c] * invN - m * m;
    float rstd = rsqrtf(var + BN_EPS);
    float sc = g[c] * rstd;
    aff[c] = sc;
    aff[64 + c] = b[c] - m * sc;
}

__global__ __launch_bounds__(256)
void final_out(const short* __restrict__ in, float* __restrict__ out, const float* __restrict__ aff)
{
    __shared__ float t[64][65];
    const int s0 = blockIdx.x * 64;
    const int tid = threadIdx.x;
    {
        const int spr = tid >> 2, ch = tid & 3;
        const short8* ip = (const short8*)(in + (size_t)(s0 + spr) * 64 + ch * 16);
        short8 v0 = ip[0], v1 = ip[1];
        #pragma unroll
        for (int q = 0; q < 8; ++q) { int c = ch * 16 + q;     t[spr][c] = bf2f(v0[q]) * aff[c] + aff[64 + c]; }
        #pragma unroll
        for (int q = 0; q < 8; ++q) { int c = ch * 16 + 8 + q; t[spr][c] = bf2f(v1[q]) * aff[c] + aff[64 + c]; }
    }
    __syncthreads();
    {
        const int c = tid >> 2, sc = (tid & 3) * 16;
        #pragma unroll
        for (int i = 0; i < 4; ++i) {
            float4 w;
            w.x = t[sc + 4 * i][c]; w.y = t[sc + 4 * i + 1][c];
            w.z = t[sc + 4 * i + 2][c]; w.w = t[sc + 4 * i + 3][c];
            *(float4*)(out + (size_t)c * DHW1 + s0 + sc + 4 * i) = w;
        }
    }
}

// ---------------------------------------------------------------------------
// merged zeroing: PadA/PadB halo edges + trash plane, X0/Y0 same, stats+biases
__global__ __launch_bounds__(256)
void zero_misc(short* __restrict__ PadA, short* __restrict__ PadB,
               short* __restrict__ X0, short* __restrict__ Y0, float* __restrict__ stats)
{
    const short8 z8 = {0, 0, 0, 0, 0, 0, 0, 0};
    int i = blockIdx.x * 256 + threadIdx.x;
    constexpr int T_F = 33 * 3104 + 76832;
    constexpr int T_X = 17 * 3136 + 40000;
    constexpr int T_Y = 17 * 1568 + 20000;
    constexpr int TOT = 2 * T_F + T_X + T_Y + 432;
    if (i >= TOT) return;

    auto fine_off = [](int q) -> size_t {
        if (q < 33 * 3104) {
            int pl = q / 3104, e = q % 3104, p = e >> 3, c = e & 7;
            int y, x;
            if (p < 98) { y = 0; x = p; }
            else if (p < 196) { y = 97; x = p - 98; }
            else { int q2 = p - 196; y = 1 + (q2 >> 1); x = (q2 & 1) ? 97 : 0; }
            return ((size_t)pl * FP_PLPTS + y * 98 + x) * 64 + c * 8;
        }
        int q2 = q - 33 * 3104;
        return (size_t)32 * FP_PLPTS * 64 + (size_t)q2 * 8;
    };
    auto co_off = [](int q, int CPR) -> size_t {
        const int EPP = 196 * CPR;
        if (q < 17 * EPP) {
            int pl = q / EPP, e = q % EPP, p = e / CPR, c = e % CPR;
            int y, x;
            if (p < 50) { y = 0; x = p; }
            else if (p < 100) { y = 49; x = p - 50; }
            else { int r = p - 100; y = 1 + (r >> 1); x = (r & 1) ? 49 : 0; }
            return ((size_t)pl * CP_PLPTS + y * 50 + x) * (CPR * 8) + c * 8;
        }
        int q2 = q - 17 * EPP;
        return (size_t)16 * CP_PLPTS * (CPR * 8) + (size_t)q2 * 8;
    };

    if (i < T_F) { *(short8*)(PadA + fine_off(i)) = z8; return; } i -= T_F;
    if (i < T_F) { *(short8*)(PadB + fine_off(i)) = z8; return; } i -= T_F;
    if (i < T_X) { *(short8*)(X0 + co_off(i, 16)) = z8; return; } i -= T_X;
    if (i < T_Y) { *(short8*)(Y0 + co_off(i, 8)) = z8; return; } i -= T_Y;
    float4 zf = {0.f, 0.f, 0.f, 0.f};
    *(float4*)((char*)stats + (size_t)i * 16) = zf;
}

// ---------------------------------------------------------------------------
// BN-fold prep for fine convs: scaled weights, bias[o], halo fill hv=-sh/sc.
template<int KSZ>
__global__ __launch_bounds__(256)
void prep_fine(const float* __restrict__ w, const float* __restrict__ aff,
               short* __restrict__ dst, float* __restrict__ bias,
               short* __restrict__ buf)
{
    __shared__ float red[256];
    constexpr int NSC = KSZ * 4096 / 256;
    int b = blockIdx.x;
    if (b < NSC) {
        int i = b * 256 + threadIdx.x;
        int t = i / 4096; int r = i & 4095; int o = r >> 6; int ci = r & 63;
        dst[i] = f2bf(w[(size_t)(o * 64 + ci) * KSZ + t] * aff[ci]);
        return;
    }
    b -= NSC;
    if (b < 64) {
        int o = b;
        float p = 0.f;
        for (int i = threadIdx.x; i < 64 * KSZ; i += 256) {
            int ci = i / KSZ, t = i % KSZ;
            p += w[(size_t)(o * 64 + ci) * KSZ + t] * aff[64 + ci];
        }
        red[threadIdx.x] = p;
        __syncthreads();
        #pragma unroll
        for (int off = 128; off > 0; off >>= 1) {
            if (threadIdx.x < off) red[threadIdx.x] += red[threadIdx.x + off];
            __syncthreads();
        }
        if (threadIdx.x == 0) bias[o] = red[0];
        return;
    }
    b -= 64;
    int q = b * 256 + threadIdx.x;
    constexpr int T_F = 33 * 3104 + 76832;
    if (q >= T_F) return;
    size_t off; int cb;
    if (q < 33 * 3104) {
        int pl = q / 3104, e = q % 3104, p = e >> 3; cb = e & 7;
        int y, x;
        if (p < 98) { y = 0; x = p; }
        else if (p < 196) { y = 97; x = p - 98; }
        else { int r = p - 196; y = 1 + (r >> 1); x = (r & 1) ? 97 : 0; }
        off = ((size_t)pl * FP_PLPTS + y * 98 + x) * 64 + cb * 8;
    } else {
        int q2 = q - 33 * 3104; cb = q2 & 7;
        off = (size_t)32 * FP_PLPTS * 64 + (size_t)q2 * 8;
    }
    short8 hv;
    #pragma unroll
    for (int k = 0; k < 8; ++k) { int c = cb * 8 + k; hv[k] = f2bf(-aff[64 + c] / aff[c]); }
    *(short8*)(buf + off) = hv;
}

// BN-fold prep for tconv: scaled w_up, per-class bias, Y0 halo fill.
__global__ __launch_bounds__(256)
void prep_up(const float* __restrict__ wup, const float* __restrict__ aff,
             short* __restrict__ dst, float* __restrict__ bias_up,
             short* __restrict__ Y0)
{
    __shared__ float red[64];
    int b = blockIdx.x;
    if (b < 432) {
        int i = b * 256 + threadIdx.x;
        int t = i / 4096; int r = i & 4095; int o = r >> 6; int ci = r & 63;
        dst[i] = f2bf(wup[(size_t)(o * 64 + ci) * 27 + t] * aff[ci]);
        return;
    }
    b -= 432;
    if (b < 512) {
        int cls = b >> 6, o = b & 63;
        int pz = (cls >> 2) & 1, py = (cls >> 1) & 1, px = cls & 1;
        int ci = threadIdx.x;
        if (ci < 64) {
            float p = 0.f;
            for (int a = 0; a <= pz; ++a) { int kd = pz ? 2 * a : 1;
                for (int b2 = 0; b2 <= py; ++b2) { int kh = py ? 2 * b2 : 1;
                    for (int c2 = 0; c2 <= px; ++c2) { int kw = px ? 2 * c2 : 1;
                        p += wup[(size_t)(o * 64 + ci) * 27 + kd * 9 + kh * 3 + kw];
                    } } }
            red[ci] = p * aff[64 + ci];
        }
        __syncthreads();
        if (threadIdx.x == 0) {
            float s = 0.f;
            for (int k = 0; k < 64; ++k) s += red[k];
            bias_up[cls * 64 + o] = s;
        }
        return;
    }
    b -= 512;
    int q = b * 256 + threadIdx.x;
    constexpr int T_Y = 17 * 1568 + 20000;
    if (q >= T_Y) return;
    size_t off; int cb;
    if (q < 17 * 1568) {
        int pl = q / 1568, e = q % 1568, p = e >> 3; cb = e & 7;
        int y, x;
        if (p < 50) { y = 0; x = p; }
        else if (p < 100) { y = 49; x = p - 50; }
        else { int r = p - 100; y = 1 + (r >> 1); x = (r & 1) ? 49 : 0; }
        off = ((size_t)pl * CP_PLPTS + y * 50 + x) * 64 + cb * 8;
    } else {
        int q2 = q - 17 * 1568; cb = q2 & 7;
        off = (size_t)16 * CP_PLPTS * 64 + (size_t)q2 * 8;
    }
    short8 hv;
    #pragma unroll
    for (int k = 0; k < 8; ++k) { int c = cb * 8 + k; hv[k] = f2bf(-aff[64 + c] / aff[c]); }
    *(short8*)(Y0 + off) = hv;
}

// ---------------------------------------------------------------------------
// Stage-A conv (CIN=128, coarse): R6-proven 2-phase counted-vmcnt kernel, MG=1.
template<int MG, int CIN, int KD, int KH, int KW, int PD, int PH, int PW,
         int GD, int GH, int GW, int OUTMODE, bool STATS>
__global__ __launch_bounds__(256, 2)
void convmm5(const short* __restrict__ A, const short* __restrict__ Wt,
             short* __restrict__ Out, float* __restrict__ stats)
{
    constexpr int MR   = 64 * MG;
    constexpr int KSZ  = KD * KH * KW;
    constexpr int PPW  = GW + 2;
    constexpr int PLP  = (GH + 2) * PPW;
    constexpr int HWg  = GH * GW;
    constexpr int CPR  = CIN / 8;
    constexpr int L2C  = (CIN == 64) ? 3 : 4;
    constexpr int RPI  = 64 / CPR;
    constexpr int ASZ  = MR * CIN * 2;
    constexpr int BSZ  = 64 * CIN * 2;
    constexpr int API  = ASZ / 4096;
    constexpr int BPI  = BSZ / 4096;
    constexpr int KCN  = CIN / 32;
    constexpr int S_IF = API + BPI;

    __shared__ char smem[2 * ASZ + 2 * BSZ];

    const int tid = threadIdx.x, lane = tid & 63, wave = tid >> 6;
    const int rl = lane & 15, kg = lane >> 4;

    const int nwg = gridDim.x;
    const int bid = blockIdx.x;
    const int bswz = (nwg & 7) ? bid : ((bid & 7) * (nwg >> 3) + (bid >> 3));
    const int row0 = bswz * MR;

    int zA[API], yxA[API], cofA[API];
    #pragma unroll
    for (int i = 0; i < API; ++i) {
        const int gi = wave * API + i;
        const int r = gi * RPI + (lane >> L2C);
        const int s = row0 + r;
        const int z = s / HWg; const int rm = s - z * HWg;
        const int y = rm / GW; const int x = rm - y * GW;
        zA[i] = z;
        yxA[i] = (y + 1) * PPW + (x + 1);
        cofA[i] = ((lane & (CPR - 1)) ^ (r & 7)) * 8;
    }
    int rB[BPI], cofB[BPI];
    #pragma unroll
    for (int i = 0; i < BPI; ++i) {
        const int gi = wave * BPI + i;
        const int r = gi * RPI + (lane >> L2C);
        rB[i] = r;
        cofB[i] = ((lane & (CPR - 1)) ^ (r & 7)) * 8;
    }

    auto stageA = [&](int bsel, int kd, int kh, int kw) {
        const int dyx = (kh - PH) * PPW + (kw - PW);
        #pragma unroll
        for (int i = 0; i < API; ++i) {
            int zp = zA[i] + (kd - PD);
            int pl = ((unsigned)zp < (unsigned)GD) ? zp : GD;
            const short* src = A + ((size_t)pl * PLP + yxA[i] + dyx) * CIN + cofA[i];
            void* dst = smem + bsel * ASZ + (wave * API + i) * 1024;
            gload16(src, dst);
        }
    };
    auto stageB = [&](int bsel, int t) {
        const short* wt = Wt + (size_t)t * 64 * CIN;
        #pragma unroll
        for (int i = 0; i < BPI; ++i) {
            const short* src = wt + rB[i] * CIN + cofB[i];
            void* dst = smem + 2 * ASZ + bsel * BSZ + (wave * BPI + i) * 1024;
            gload16(src, dst);
        }
    };

    f32x4 acc[MG][4];
    #pragma unroll
    for (int mg = 0; mg < MG; ++mg)
        #pragma unroll
        for (int ng = 0; ng < 4; ++ng)
            acc[mg][ng] = (f32x4){0.f, 0.f, 0.f, 0.f};

    auto comp = [&](int bsel) {
        const short* ab = (const short*)(smem + bsel * ASZ);
        const short* bb = (const short*)(smem + 2 * ASZ + bsel * BSZ);
        #pragma unroll
        for (int kc = 0; kc < KCN; ++kc) {
            short8 av[MG], bv[4];
            #pragma unroll
            for (int mg = 0; mg < MG; ++mg) {
                const int r = wave * (16 * MG) + mg * 16 + rl;
                const int c = (kc * 4 + kg) ^ (r & 7);
                av[mg] = *(const short8*)(ab + r * CIN + c * 8);
            }
            #pragma unroll
            for (int ng = 0; ng < 4; ++ng) {
                const int r = ng * 16 + rl;
                const int c = (kc * 4 + kg) ^ (r & 7);
                bv[ng] = *(const short8*)(bb + r * CIN + c * 8);
            }
            __builtin_amdgcn_s_setprio(1);
            #pragma unroll
            for (int mg = 0; mg < MG; ++mg)
                #pragma unroll
                for (int ng = 0; ng < 4; ++ng)
                    acc[mg][ng] = __builtin_amdgcn_mfma_f32_16x16x32_bf16(av[mg], bv[ng], acc[mg][ng], 0, 0, 0);
            __builtin_amdgcn_s_setprio(0);
        }
    };

    stageA(0, 0, 0, 0);
    stageB(0, 0);

    #pragma unroll
    for (int t = 0; t < KSZ; ++t) {
        const int cur = t & 1;
        if (t + 1 < KSZ) {
            const int t1 = t + 1;
            const int kd = t1 / (KH * KW), rm = t1 % (KH * KW);
            stageA(cur ^ 1, kd, rm / KW, rm % KW);
            stageB(cur ^ 1, t1);
            asm volatile("s_waitcnt vmcnt(%0)" :: "i"(S_IF) : "memory");
        } else {
            asm volatile("s_waitcnt vmcnt(0)" ::: "memory");
        }
        __builtin_amdgcn_s_barrier();
        __builtin_amdgcn_sched_barrier(0);
        comp(cur);
        asm volatile("s_waitcnt lgkmcnt(0)" ::: "memory");
        __builtin_amdgcn_sched_barrier(0);
        __builtin_amdgcn_s_barrier();
    }

    short (*tile)[64] = (short(*)[64])smem;
    float* red = (float*)(smem + 2 * ASZ);

    #pragma unroll
    for (int mg = 0; mg < MG; ++mg)
        #pragma unroll
        for (int ng = 0; ng < 4; ++ng)
            #pragma unroll
            for (int j = 0; j < 4; ++j) {
                float v = acc[mg][ng][j];
                if (STATS) v = (v >= 0.f) ? v : SLOPE * v;
                tile[wave * (16 * MG) + mg * 16 + kg * 4 + j][ng * 16 + rl] = f2bf(v);
            }
    __syncthreads();

    #pragma unroll
    for (int i = 0; i < MR / 32; ++i) {
        const int chunk = i * 256 + tid;
        const int r = chunk >> 3, cc = (chunk & 7) * 8;
        const int s = row0 + r;
        size_t o;
        if (OUTMODE == 0)      o = (size_t)s * 64 + cc;
        else if (OUTMODE == 1) o = (size_t)pidx_fine(s) * 64 + cc;
        else                   o = (size_t)pidx_coarse(s) * 64 + cc;
        *(short8*)(Out + o) = *(const short8*)&tile[r][cc];
    }

    if (STATS) {
        float s1 = 0.f, s2 = 0.f;
        const int col = tid & 63, rg = tid >> 6;
        #pragma unroll 4
        for (int r = rg * (MR / 4); r < (rg + 1) * (MR / 4); ++r) {
            float v = bf2f(tile[r][col]); s1 += v; s2 += v * v;
        }
        red[rg * 64 + col] = s1;
        red[256 + rg * 64 + col] = s2;
        __syncthreads();
        if (tid < 64) {
            float a = red[tid] + red[64 + tid] + red[128 + tid] + red[192 + tid];
            float b = red[256 + tid] + red[320 + tid] + red[384 + tid] + red[448 + tid];
            atomicAdd(&stats[tid], a);
            atomicAdd(&stats[64 + tid], b);
        }
    }
}

// ---------------------------------------------------------------------------
// Fine convs (C/D/E): R8-proven convmm7 (A+B in LDS, per-tap dbuf, counted
// vmcnt, 2 barriers/tap) + BN-fold bias-initialized accumulator.
template<int KD, int KH, int PD, int PH, int OUTMODE>
__global__ __launch_bounds__(128, 1)
void convmm7(const short* __restrict__ A, const short* __restrict__ Wt,
             const float* __restrict__ bias,
             short* __restrict__ Out, float* __restrict__ stats)
{
    constexpr int KSZ = KD * KH * 3, NG = KD * KH;
    constexpr int PLP = FP_PLPTS;
    constexpr int ABYTES = 208 * 128;     // 26624
    constexpr int BBYTES = 8192;
    __shared__ __align__(16) char smem[2 * ABYTES + 2 * BBYTES];   // 69632

    const int tid = threadIdx.x, lane = tid & 63, wave = tid >> 6;  // wave 0..1
    const int rl = lane & 15, kg = lane >> 4;

    const int nwg = gridDim.x, bid = blockIdx.x;
    const int bswz = (bid & 7) * (nwg >> 3) + (bid >> 3);
    const int s0 = bswz * 192;
    const int z0 = s0 / HW1;
    const int y0 = (s0 - z0 * HW1) / 96;

    const int ptl = lane >> 3;
    const int csl = (lane & 7) ^ ptl;

    auto stageA = [&](int bsel, int g) {
        const int kd = g / KH, kh = g % KH;
        const int zp = z0 + kd - PD;
        const int pl = ((unsigned)zp < 32u) ? zp : 32;   // trash plane (hv/zero)
        const int ys = y0 + kh - PH;
        const size_t base = (size_t)pl * PLP + (size_t)(ys + 1) * 98;
        #pragma unroll
        for (int i = 0; i < 13; ++i) {
            const int ii = wave * 13 + i;
            const short* src = A + (base + ii * 8 + ptl) * 64 + csl * 8;
            gload16(src, smem + bsel * ABYTES + ii * 1024);
        }
    };
    auto stageB = [&](int bsel, int t) {
        const short* wt = Wt + (size_t)t * 4096;
        #pragma unroll
        for (int i = 0; i < 4; ++i) {
            const int ii = wave * 4 + i;
            const short* src = wt + (ii * 8 + ptl) * 64 + csl * 8;
            gload16(src, smem + 2 * ABYTES + bsel * BBYTES + ii * 1024);
        }
    };

    float bc[4];
    #pragma unroll
    for (int ng = 0; ng < 4; ++ng) bc[ng] = bias[ng * 16 + rl];
    f32x4 acc[6][4];
    #pragma unroll
    for (int mg = 0; mg < 6; ++mg)
        #pragma unroll
        for (int ng = 0; ng < 4; ++ng)
            acc[mg][ng] = (f32x4){bc[ng], bc[ng], bc[ng], bc[ng]};

    const int jb = wave * 98 + rl;

    stageA(0, 0);
    stageB(0, 0);

    #pragma unroll
    for (int t = 0; t < KSZ; ++t) {
        const int g = t / 3, kw = t % 3;
        if (kw == 0 && g + 1 < NG) stageA((g + 1) & 1, g + 1);
        if (t + 1 < KSZ) stageB((t + 1) & 1, t + 1);
        if (t == KSZ - 1)
            asm volatile("s_waitcnt vmcnt(0)" ::: "memory");
        else if (kw == 0 && g + 1 < NG)
            asm volatile("s_waitcnt vmcnt(17)" ::: "memory");
        else
            asm volatile("s_waitcnt vmcnt(4)" ::: "memory");
        __builtin_amdgcn_s_barrier();
        __builtin_amdgcn_sched_barrier(0);

        const char* ab = smem + (g & 1) * ABYTES;
        const char* bb = smem + 2 * ABYTES + (t & 1) * BBYTES;
        #pragma unroll
        for (int kc = 0; kc < 2; ++kc) {
            short8 bv[4], av[6];
            #pragma unroll
            for (int ng = 0; ng < 4; ++ng) {
                const int row = ng * 16 + rl;
                bv[ng] = *(const short8*)(bb + row * 128 + (((kc * 4 + kg) ^ (rl & 7)) << 4));
            }
            #pragma unroll
            for (int mg = 0; mg < 6; ++mg) {
                const int j = jb + mg * 16 + kw;
                av[mg] = *(const short8*)(ab + j * 128 + (((kc * 4 + kg) ^ (j & 7)) << 4));
            }
            __builtin_amdgcn_s_setprio(1);
            #pragma unroll
            for (int mg = 0; mg < 6; ++mg)
                #pragma unroll
                for (int ng = 0; ng < 4; ++ng)
                    acc[mg][ng] = __builtin_amdgcn_mfma_f32_16x16x32_bf16(av[mg], bv[ng], acc[mg][ng], 0, 0, 0);
            __builtin_amdgcn_s_setprio(0);
        }
        asm volatile("s_waitcnt lgkmcnt(0)" ::: "memory");
        __builtin_amdgcn_sched_barrier(0);
        __builtin_amdgcn_s_barrier();
    }

    short (*tile)[64] = (short(*)[64])smem;
    float* red = (float*)(smem + 192 * 64 * 2);

    #pragma unroll
    for (int mg = 0; mg < 6; ++mg)
        #pragma unroll
        for (int ng = 0; ng < 4; ++ng)
            #pragma unroll
            for (int j = 0; j < 4; ++j) {
                float v = acc[mg][ng][j];
                v = (v >= 0.f) ? v : SLOPE * v;
                tile[wave * 96 + mg * 16 + kg * 4 + j][ng * 16 + rl] = f2bf(v);
            }
    __syncthreads();

    #pragma unroll
    for (int i = 0; i < 12; ++i) {
        const int chunk = i * 128 + tid;
        const int r = chunk >> 3, cc = (chunk & 7) * 8;
        const int s = s0 + r;
        size_t o;
        if (OUTMODE == 0) o = (size_t)s * 64 + cc;
        else              o = (size_t)pidx_fine(s) * 64 + cc;
        *(short8*)(Out + o) = *(const short8*)&tile[r][cc];
    }

    {
        float s1 = 0.f, s2 = 0.f;
        const int col = tid & 63, rg = tid >> 6;
        #pragma unroll 4
        for (int r = rg * 96; r < rg * 96 + 96; ++r) {
            float v = bf2f(tile[r][col]); s1 += v; s2 += v * v;
        }
        red[rg * 64 + col] = s1;
        red[128 + rg * 64 + col] = s2;
        __syncthreads();
        if (tid < 64) {
            atomicAdd(&stats[tid], red[tid] + red[64 + tid]);
            atomicAdd(&stats[64 + tid], red[128 + tid] + red[192 + tid]);
        }
    }
}

// ---------------------------------------------------------------------------
// Transposed conv by output-parity class (R6-proven) + per-class BN-fold bias.
__global__ __launch_bounds__(256, 2)
void tconv_cls(const short* __restrict__ Y, const short* __restrict__ Wt,
               const float* __restrict__ bias_up,
               const short* __restrict__ SK, short* __restrict__ Out)
{
    const int cls = blockIdx.y;
    const int pz = (cls >> 2) & 1, py = (cls >> 1) & 1, px = cls & 1;
    const int tid = threadIdx.x, lane = tid & 63, wave = tid >> 6;
    const int rl = lane & 15, kg = lane >> 4;
    const int row0 = blockIdx.x * 256;

    int zin0[4], zin1[4];
    #pragma unroll
    for (int mg = 0; mg < 4; ++mg) {
        int s = row0 + wave * 64 + mg * 16 + rl;
        int zc = s / HW0; int r = s - zc * HW0; int yc = r / W0; int xc = r - yc * W0;
        int ib = ((yc + 1) * 50 + (xc + 1)) * 64 + kg * 8;
        zin0[mg] = zc * (CP_PLPTS * 64) + ib;
        zin1[mg] = ((zc + 1 < 16) ? zc + 1 : 16) * (CP_PLPTS * 64) + ib;
    }
    const int boff = rl * 64 + kg * 8;

    float bc[4];
    #pragma unroll
    for (int ng = 0; ng < 4; ++ng) bc[ng] = bias_up[cls * 64 + ng * 16 + rl];
    f32x4 acc[4][4];
    #pragma unroll
    for (int mg = 0; mg < 4; ++mg)
        #pragma unroll
        for (int ng = 0; ng < 4; ++ng)
            acc[mg][ng] = (f32x4){bc[ng], bc[ng], bc[ng], bc[ng]};

    for (int a = 0; a <= pz; ++a) {
        const int kd = pz ? 2 * a : 1;
        for (int b = 0; b <= py; ++b) {
            const int kh = py ? 2 * b : 1;
            for (int c = 0; c <= px; ++c) {
                const int kw = px ? 2 * c : 1;
                const int t = kd * 9 + kh * 3 + kw;
                const int dlt = (b * 50 + c) * 64;
                int ao[4];
                #pragma unroll
                for (int mg = 0; mg < 4; ++mg)
                    ao[mg] = (a ? zin1[mg] : zin0[mg]) + dlt;
                #pragma unroll
                for (int kc = 0; kc < 2; ++kc) {
                    short8 av[4], bv[4];
                    #pragma unroll
                    for (int mg = 0; mg < 4; ++mg)
                        av[mg] = *(const short8*)(Y + ao[mg] + kc * 32);
                    #pragma unroll
                    for (int ng = 0; ng < 4; ++ng)
                        bv[ng] = *(const short8*)(Wt + (t * 64 + ng * 16) * 64 + boff + kc * 32);
                    #pragma unroll
                    for (int mg = 0; mg < 4; ++mg)
                        #pragma unroll
                        for (int ng = 0; ng < 4; ++ng)
                            acc[mg][ng] = __builtin_amdgcn_mfma_f32_16x16x32_bf16(av[mg], bv[ng], acc[mg][ng], 0, 0, 0);
                }
            }
        }
    }

    __shared__ short tile[256][72];
    #pragma unroll
    for (int mg = 0; mg < 4; ++mg)
        #pragma unroll
        for (int ng = 0; ng < 4; ++ng)
            #pragma unroll
            for (int j = 0; j < 4; ++j)
                tile[wave * 64 + mg * 16 + kg * 4 + j][ng * 16 + rl] = f2bf(acc[mg][ng][j]);
    __syncthreads();

    #pragma unroll
    for (int i = 0; i < 8; ++i) {
        int chunk = i * 256 + tid;
        int r = chunk >> 3, cc = (chunk & 7) * 8;
        int sl = row0 + r;
        int zc = sl / HW0; int rr = sl - zc * HW0; int yc = rr / W0; int xc = rr - yc * W0;
        int z = 2 * zc + pz, y = 2 * yc + py, x = 2 * xc + px;
        size_t so = (size_t)((z * H1 + y) * W1_ + x) * 64 + cc;
        size_t po = (size_t)(z * FP_PLPTS + (y + 1) * 98 + (x + 1)) * 64 + cc;
        short8 v = *(const short8*)&tile[r][cc];
        short8 skv = *(const short8*)(SK + so);
        short8 o;
        #pragma unroll
        for (int q = 0; q < 8; ++q) o[q] = f2bf(bf2f(v[q]) + bf2f(skv[q]));
        *(short8*)(Out + po) = o;
    }
}

// ---------------------------------------------------------------------------
extern "C" void kernel_launch(void* const* d_in, const int* in_sizes, int n_in,
                              void* d_out, int out_size, void* d_ws, size_t ws_size,
                              hipStream_t stream)
{
    const float* x       = (const float*)d_in[0];
    const float* skip    = (const float*)d_in[1];
    const float* w_trans = (const float*)d_in[2];
    const float* g_t     = (const float*)d_in[3];
    const float* b_t     = (const float*)d_in[4];
    const float* w_up    = (const float*)d_in[5];
    const float* w1      = (const float*)d_in[6];
    const float* g1      = (const float*)d_in[7];
    const float* b1      = (const float*)d_in[8];
    const float* w2      = (const float*)d_in[9];
    const float* g2      = (const float*)d_in[10];
    const float* b2      = (const float*)d_in[11];
    const float* w3      = (const float*)d_in[12];
    const float* g3      = (const float*)d_in[13];
    const float* b3      = (const float*)d_in[14];
    float* out = (float*)d_out;

    char* ws = (char*)d_ws;
    short* PadA = (short*)ws;
    short* PadB = (short*)(ws + (size_t)FP_ELEMS * 2);
    float* stats = (float*)(ws + (size_t)FP_ELEMS * 4);

    float* st0 = stats;       float* af0 = stats + 512;
    float* st1 = stats + 128; float* af1 = stats + 512 + 128;
    float* st2 = stats + 256; float* af2 = stats + 512 + 256;
    float* st3 = stats + 384; float* af3 = stats + 512 + 384;
    float* bias2 = stats + 1024;
    float* bias3 = stats + 1088;
    float* bias_up = stats + 1152;   // 8*64
    float* bias_z  = stats + 1664;   // zeros (for conv C)

    char* ob = (char*)d_out;
    short* X0  = (short*)ob;
    short* Y0  = (short*)(ob + 10880000);
    short* SKb = (short*)(ob + 16320000);
    short* wt_t  = (short*)(ob + 54068736);
    short* wt_up = wt_t + 221184;
    short* wt_1  = wt_up + 110592;
    short* wt_2  = wt_1 + 36864;
    short* wt_3  = wt_2 + 36864;

    constexpr int T_F = 33 * 3104 + 76832;
    constexpr int T_X = 17 * 3136 + 40000;
    constexpr int T_Y = 17 * 1568 + 20000;
    zero_misc<<<(2 * T_F + T_X + T_Y + 432 + 255) / 256, 256, 0, stream>>>(PadA, PadB, X0, Y0, stats);

    // unscaled repacks (stage A weights + conv-C weights)
    prep_all<<<(221184 + 36864 + 255) / 256, 256, 0, stream>>>(w_trans, w1, wt_t, wt_1);

    // input transposes
    to_cl_pad128<<<dim3(DHW0 / 64, 2), 256, 0, stream>>>(x, X0);
    to_cl_bf16<<<DHW1 / 64, 256, 0, stream>>>(skip, SKb, DHW1);

    // stage A: subm 3x3x3 CIN=128 coarse -> Y0pad (raw lrelu) + stats
    convmm5<1, 128, 3, 3, 3, 1, 1, 1, 16, 48, 48, 2, true>
        <<<DHW0 / 64, 256, 0, stream>>>(X0, wt_t, Y0, st0);
    finalize_stats<<<1, 64, 0, stream>>>(st0, g_t, b_t, 1.f / DHW0, af0);
    // fold af0: scaled w_up + per-class bias + Y0 halo fill
    prep_up<<<432 + 512 + (T_Y + 255) / 256, 256, 0, stream>>>(w_up, af0, wt_up, bias_up, Y0);

    // stage B: transposed conv by parity class (+bias) + skip -> PadA
    tconv_cls<<<dim3(DHW0 / 256, 8), 256, 0, stream>>>(Y0, wt_up, bias_up, SKb, PadA);

    // stage C: conv (1,3,3) pad (0,1,1) -> PadB raw + stats (zero bias)
    convmm7<1, 3, 0, 1, 1>
        <<<DHW1 / 192, 128, 0, stream>>>(PadA, wt_1, bias_z, PadB, st1);
    finalize_stats<<<1, 64, 0, stream>>>(st1, g1, b1, 1.f / DHW1, af1);
    // fold af1: scaled w2 + bias2 + PadB halo fill
    prep_fine<9><<<144 + 64 + (T_F + 255) / 256, 256, 0, stream>>>(w2, af1, wt_2, bias2, PadB);

    // stage D: conv (3,1,3) pad (1,0,1) -> PadA raw + stats
    convmm7<3, 1, 1, 0, 1>
        <<<DHW1 / 192, 128, 0, stream>>>(PadB, wt_2, bias2, PadA, st2);
    finalize_stats<<<1, 64, 0, stream>>>(st2, g2, b2, 1.f / DHW1, af2);
    // fold af2: scaled w3 + bias3 + PadA halo fill
    prep_fine<27><<<432 + 64 + (T_F + 255) / 256, 256, 0, stream>>>(w3, af2, wt_3, bias3, PadA);

    // stage E: conv (3,3,3) pad 1 -> PadB COMPACT raw + stats
    convmm7<3, 3, 1, 1, 0>
        <<<DHW1 / 192, 128, 0, stream>>>(PadA, wt_3, bias3, PadB, st3);
    finalize_stats<<<1, 64, 0, stream>>>(st3, g3, b3, 1.f / DHW1, af3);

    // final: aff3 + transpose to NCDHW fp32
    final_out<<<DHW1 / 64, 256, 0, stream>>>(PadB, out, af3);
}

// Round 11
// 385.283 us; speedup vs baseline: 1.1538x; 1.0220x over previous
//
#include <hip/hip_runtime.h>

#define SLOPE 0.01f
#define BN_EPS 1e-5f

typedef __attribute__((ext_vector_type(8))) short short8;
typedef __attribute__((ext_vector_type(4))) float f32x4;

static constexpr int D1 = 32, H1 = 96, W1_ = 96;
static constexpr int HW1 = H1 * W1_, DHW1 = D1 * HW1;        // 294912
static constexpr int D0 = 16, H0 = 48, W0 = 48;
static constexpr int HW0 = H0 * W0, DHW0 = D0 * HW0;         // 36864

static constexpr int FP_PLPTS = 98 * 98;
static constexpr int CP_PLPTS = 50 * 50;
static constexpr int FP_ELEMS = 33 * FP_PLPTS * 64;

static constexpr int T_F = 33 * 3104 + 76832;   // fine pad: edge+trash chunks
static constexpr int T_X = 17 * 3136 + 40000;   // X0
static constexpr int T_Y = 17 * 1568 + 20000;   // Y0

__device__ __forceinline__ short f2bf(float f) {
    unsigned u = __builtin_bit_cast(unsigned, f);
    unsigned r = (u + 0x7fffu + ((u >> 16) & 1u)) >> 16;
    return (short)r;
}
__device__ __forceinline__ float bf2f(short s) {
    unsigned u = ((unsigned)(unsigned short)s) << 16;
    return __builtin_bit_cast(float, u);
}
__device__ __forceinline__ int pidx_fine(int s) {
    int z = s / HW1; int r = s - z * HW1; int y = r / W1_; int x = r - y * W1_;
    return z * FP_PLPTS + (y + 1) * 98 + (x + 1);
}
__device__ __forceinline__ int pidx_coarse(int s) {
    int z = s / HW0; int r = s - z * HW0; int y = r / W0; int x = r - y * W0;
    return z * CP_PLPTS + (y + 1) * 50 + (x + 1);
}
__device__ __forceinline__ void gload16(const void* g, void* l) {
    __builtin_amdgcn_global_load_lds(
        (const __attribute__((address_space(1))) void*)g,
        (__attribute__((address_space(3))) void*)l, 16, 0, 0);
}

// ---------------------------------------------------------------------------
// MEGA-PREP: zero halos/trash/stats | weight repacks | x transpose | skip transpose
// All regions disjoint -> one kernel, branches by blockIdx.
static constexpr int NB_Z = (2 * T_F + T_X + T_Y + 432 + 255) / 256;   // 1950
static constexpr int NB_W = (221184 + 36864 + 255) / 256;              // 1008
static constexpr int NB_P = 1152;   // x -> X0pad (576 x 2)
static constexpr int NB_S = DHW1 / 64;  // 4608 skip -> SKb

__global__ __launch_bounds__(256)
void prep0(const float* __restrict__ x, const float* __restrict__ skip,
           const float* __restrict__ w_trans, const float* __restrict__ w1,
           short* __restrict__ PadA, short* __restrict__ PadB,
           short* __restrict__ X0, short* __restrict__ Y0,
           float* __restrict__ stats, short* __restrict__ wt_t,
           short* __restrict__ wt_1, short* __restrict__ SKb)
{
    __shared__ float t[64][65];
    int b = blockIdx.x;
    const int tid = threadIdx.x;

    if (b < NB_Z) {
        const short8 z8 = {0, 0, 0, 0, 0, 0, 0, 0};
        int i = b * 256 + tid;
        constexpr int TOT = 2 * T_F + T_X + T_Y + 432;
        if (i >= TOT) return;
        auto fine_off = [](int q) -> size_t {
            if (q < 33 * 3104) {
                int pl = q / 3104, e = q % 3104, p = e >> 3, c = e & 7;
                int y, xx;
                if (p < 98) { y = 0; xx = p; }
                else if (p < 196) { y = 97; xx = p - 98; }
                else { int q2 = p - 196; y = 1 + (q2 >> 1); xx = (q2 & 1) ? 97 : 0; }
                return ((size_t)pl * FP_PLPTS + y * 98 + xx) * 64 + c * 8;
            }
            int q2 = q - 33 * 3104;
            return (size_t)32 * FP_PLPTS * 64 + (size_t)q2 * 8;
        };
        auto co_off = [](int q, int CPR) -> size_t {
            const int EPP = 196 * CPR;
            if (q < 17 * EPP) {
                int pl = q / EPP, e = q % EPP, p = e / CPR, c = e % CPR;
                int y, xx;
                if (p < 50) { y = 0; xx = p; }
                else if (p < 100) { y = 49; xx = p - 50; }
                else { int r = p - 100; y = 1 + (r >> 1); xx = (r & 1) ? 49 : 0; }
                return ((size_t)pl * CP_PLPTS + y * 50 + xx) * (CPR * 8) + c * 8;
            }
            int q2 = q - 17 * EPP;
            return (size_t)16 * CP_PLPTS * (CPR * 8) + (size_t)q2 * 8;
        };
        if (i < T_F) { *(short8*)(PadA + fine_off(i)) = z8; return; } i -= T_F;
        if (i < T_F) { *(short8*)(PadB + fine_off(i)) = z8; return; } i -= T_F;
        if (i < T_X) { *(short8*)(X0 + co_off(i, 16)) = z8; return; } i -= T_X;
        if (i < T_Y) { *(short8*)(Y0 + co_off(i, 8)) = z8; return; } i -= T_Y;
        float4 zf = {0.f, 0.f, 0.f, 0.f};
        *(float4*)((char*)stats + (size_t)i * 16) = zf;
        return;
    }
    b -= NB_Z;

    if (b < NB_W) {
        int i = b * 256 + tid;
        if (i < 221184) {
            int tt = i / 8192; int r = i % 8192; int o = r >> 7; int ci = r & 127;
            wt_t[i] = f2bf(w_trans[(size_t)(o * 128 + ci) * 27 + tt]);
            return;
        }
        i -= 221184;
        if (i < 36864) {
            int tt = i / 4096; int r = i & 4095; int o = r >> 6; int ci = r & 63;
            wt_1[i] = f2bf(w1[(size_t)(o * 64 + ci) * 9 + tt]);
        }
        return;
    }
    b -= NB_W;

    if (b < NB_P) {
        const int s0 = (b % 576) * 64, c0 = (b / 576) * 64;
        {
            const int cpr = tid >> 2, ch = tid & 3;
            const float4* ip = (const float4*)(x + (size_t)(c0 + cpr) * DHW0 + s0 + ch * 16);
            #pragma unroll
            for (int i = 0; i < 4; ++i) {
                float4 v = ip[i]; int sb = ch * 16 + i * 4;
                t[sb][cpr] = v.x; t[sb + 1][cpr] = v.y; t[sb + 2][cpr] = v.z; t[sb + 3][cpr] = v.w;
            }
        }
        __syncthreads();
        {
            const int spr = tid >> 2, cc = (tid & 3) * 16;
            short8 o0, o1;
            #pragma unroll
            for (int q = 0; q < 8; ++q) { o0[q] = f2bf(t[spr][cc + q]); o1[q] = f2bf(t[spr][cc + 8 + q]); }
            const int p = pidx_coarse(s0 + spr);
            short* op = X0 + (size_t)p * 128 + c0 + cc;
            *(short8*)op = o0;
            *(short8*)(op + 8) = o1;
        }
        return;
    }
    b -= NB_P;

    {
        const int s0 = b * 64;
        {
            const int cpr = tid >> 2, ch = tid & 3;
            const float4* ip = (const float4*)(skip + (size_t)cpr * DHW1 + s0 + ch * 16);
            #pragma unroll
            for (int i = 0; i < 4; ++i) {
                float4 v = ip[i]; int sb = ch * 16 + i * 4;
                t[sb][cpr] = v.x; t[sb + 1][cpr] = v.y; t[sb + 2][cpr] = v.z; t[sb + 3][cpr] = v.w;
            }
        }
        __syncthreads();
        {
            const int spr = tid >> 2, cc = (tid & 3) * 16;
            short8 o0, o1;
            #pragma unroll
            for (int q = 0; q < 8; ++q) { o0[q] = f2bf(t[spr][cc + q]); o1[q] = f2bf(t[spr][cc + 8 + q]); }
            short* op = SKb + (size_t)(s0 + spr) * 64 + cc;
            *(short8*)op = o0;
            *(short8*)(op + 8) = o1;
        }
    }
}

// ---------------------------------------------------------------------------
// per-block aff recompute helper (replaces finalize_stats)
__device__ __forceinline__ void compute_aff(const float* __restrict__ st,
                                            const float* __restrict__ g,
                                            const float* __restrict__ bb,
                                            float invN, float* sa, int tid)
{
    if (tid < 64) {
        int c = tid;
        float m = st[c] * invN;
        float var = st[64 + c] * invN - m * m;
        float sc = g[c] * rsqrtf(var + BN_EPS);
        sa[c] = sc;
        sa[64 + c] = bb[c] - m * sc;
    }
    __syncthreads();
}

// final: E-raw compact bf16 --aff3(from stats)--> out NCDHW fp32
__global__ __launch_bounds__(256)
void final_out(const short* __restrict__ in, float* __restrict__ out,
               const float* __restrict__ st, const float* __restrict__ g,
               const float* __restrict__ bb)
{
    __shared__ float t[64][65];
    __shared__ float sa[128];
    const int s0 = blockIdx.x * 64;
    const int tid = threadIdx.x;
    compute_aff(st, g, bb, 1.f / DHW1, sa, tid);
    {
        const int spr = tid >> 2, ch = tid & 3;
        const short8* ip = (const short8*)(in + (size_t)(s0 + spr) * 64 + ch * 16);
        short8 v0 = ip[0], v1 = ip[1];
        #pragma unroll
        for (int q = 0; q < 8; ++q) { int c = ch * 16 + q;     t[spr][c] = bf2f(v0[q]) * sa[c] + sa[64 + c]; }
        #pragma unroll
        for (int q = 0; q < 8; ++q) { int c = ch * 16 + 8 + q; t[spr][c] = bf2f(v1[q]) * sa[c] + sa[64 + c]; }
    }
    __syncthreads();
    {
        const int c = tid >> 2, sc = (tid & 3) * 16;
        #pragma unroll
        for (int i = 0; i < 4; ++i) {
            float4 w;
            w.x = t[sc + 4 * i][c]; w.y = t[sc + 4 * i + 1][c];
            w.z = t[sc + 4 * i + 2][c]; w.w = t[sc + 4 * i + 3][c];
            *(float4*)(out + (size_t)c * DHW1 + s0 + sc + 4 * i) = w;
        }
    }
}

// ---------------------------------------------------------------------------
// BN-fold prep (fused finalize_stats): scaled weights, bias[o], halo fill.
template<int KSZ>
__global__ __launch_bounds__(256)
void prep_fine(const float* __restrict__ w, const float* __restrict__ st,
               const float* __restrict__ g, const float* __restrict__ bb,
               short* __restrict__ dst, float* __restrict__ bias,
               short* __restrict__ buf)
{
    __shared__ float red[256];
    __shared__ float sa[128];
    const int tid = threadIdx.x;
    compute_aff(st, g, bb, 1.f / DHW1, sa, tid);

    constexpr int NSC = KSZ * 4096 / 256;
    int b = blockIdx.x;
    if (b < NSC) {
        int i = b * 256 + tid;
        int t = i / 4096; int r = i & 4095; int o = r >> 6; int ci = r & 63;
        dst[i] = f2bf(w[(size_t)(o * 64 + ci) * KSZ + t] * sa[ci]);
        return;
    }
    b -= NSC;
    if (b < 64) {
        int o = b;
        float p = 0.f;
        for (int i = tid; i < 64 * KSZ; i += 256) {
            int ci = i / KSZ, t = i % KSZ;
            p += w[(size_t)(o * 64 + ci) * KSZ + t] * sa[64 + ci];
        }
        red[tid] = p;
        __syncthreads();
        #pragma unroll
        for (int off = 128; off > 0; off >>= 1) {
            if (tid < off) red[tid] += red[tid + off];
            __syncthreads();
        }
        if (tid == 0) bias[o] = red[0];
        return;
    }
    b -= 64;
    int q = b * 256 + tid;
    if (q >= T_F) return;
    size_t off; int cb;
    if (q < 33 * 3104) {
        int pl = q / 3104, e = q % 3104, p = e >> 3; cb = e & 7;
        int y, xx;
        if (p < 98) { y = 0; xx = p; }
        else if (p < 196) { y = 97; xx = p - 98; }
        else { int r = p - 196; y = 1 + (r >> 1); xx = (r & 1) ? 97 : 0; }
        off = ((size_t)pl * FP_PLPTS + y * 98 + xx) * 64 + cb * 8;
    } else {
        int q2 = q - 33 * 3104; cb = q2 & 7;
        off = (size_t)32 * FP_PLPTS * 64 + (size_t)q2 * 8;
    }
    short8 hv;
    #pragma unroll
    for (int k = 0; k < 8; ++k) { int c = cb * 8 + k; hv[k] = f2bf(-sa[64 + c] / sa[c]); }
    *(short8*)(buf + off) = hv;
}

// BN-fold prep for tconv (fused finalize_stats of stage A).
__global__ __launch_bounds__(256)
void prep_up(const float* __restrict__ wup, const float* __restrict__ st,
             const float* __restrict__ g, const float* __restrict__ bb,
             short* __restrict__ dst, float* __restrict__ bias_up,
             short* __restrict__ Y0)
{
    __shared__ float red[64];
    __shared__ float sa[128];
    const int tid = threadIdx.x;
    compute_aff(st, g, bb, 1.f / DHW0, sa, tid);

    int b = blockIdx.x;
    if (b < 432) {
        int i = b * 256 + tid;
        int t = i / 4096; int r = i & 4095; int o = r >> 6; int ci = r & 63;
        dst[i] = f2bf(wup[(size_t)(o * 64 + ci) * 27 + t] * sa[ci]);
        return;
    }
    b -= 432;
    if (b < 512) {
        int cls = b >> 6, o = b & 63;
        int pz = (cls >> 2) & 1, py = (cls >> 1) & 1, px = cls & 1;
        int ci = tid;
        if (ci < 64) {
            float p = 0.f;
            for (int a = 0; a <= pz; ++a) { int kd = pz ? 2 * a : 1;
                for (int b2 = 0; b2 <= py; ++b2) { int kh = py ? 2 * b2 : 1;
                    for (int c2 = 0; c2 <= px; ++c2) { int kw = px ? 2 * c2 : 1;
                        p += wup[(size_t)(o * 64 + ci) * 27 + kd * 9 + kh * 3 + kw];
                    } } }
            red[ci] = p * sa[64 + ci];
        }
        __syncthreads();
        if (tid == 0) {
            float s = 0.f;
            for (int k = 0; k < 64; ++k) s += red[k];
            bias_up[cls * 64 + o] = s;
        }
        return;
    }
    b -= 512;
    int q = b * 256 + tid;
    if (q >= T_Y) return;
    size_t off; int cb;
    if (q < 17 * 1568) {
        int pl = q / 1568, e = q % 1568, p = e >> 3; cb = e & 7;
        int y, xx;
        if (p < 50) { y = 0; xx = p; }
        else if (p < 100) { y = 49; xx = p - 50; }
        else { int r = p - 100; y = 1 + (r >> 1); xx = (r & 1) ? 49 : 0; }
        off = ((size_t)pl * CP_PLPTS + y * 50 + xx) * 64 + cb * 8;
    } else {
        int q2 = q - 17 * 1568; cb = q2 & 7;
        off = (size_t)16 * CP_PLPTS * 64 + (size_t)q2 * 8;
    }
    short8 hv;
    #pragma unroll
    for (int k = 0; k < 8; ++k) { int c = cb * 8 + k; hv[k] = f2bf(-sa[64 + c] / sa[c]); }
    *(short8*)(Y0 + off) = hv;
}

// ---------------------------------------------------------------------------
// Stage-A conv (CIN=128, coarse): R6-proven 2-phase counted-vmcnt kernel, MG=1.
template<int MG, int CIN, int KD, int KH, int KW, int PD, int PH, int PW,
         int GD, int GH, int GW, int OUTMODE, bool STATS>
__global__ __launch_bounds__(256, 2)
void convmm5(const short* __restrict__ A, const short* __restrict__ Wt,
             short* __restrict__ Out, float* __restrict__ stats)
{
    constexpr int MR   = 64 * MG;
    constexpr int KSZ  = KD * KH * KW;
    constexpr int PPW  = GW + 2;
    constexpr int PLP  = (GH + 2) * PPW;
    constexpr int HWg  = GH * GW;
    constexpr int CPR  = CIN / 8;
    constexpr int L2C  = (CIN == 64) ? 3 : 4;
    constexpr int RPI  = 64 / CPR;
    constexpr int ASZ  = MR * CIN * 2;
    constexpr int BSZ  = 64 * CIN * 2;
    constexpr int API  = ASZ / 4096;
    constexpr int BPI  = BSZ / 4096;
    constexpr int KCN  = CIN / 32;
    constexpr int S_IF = API + BPI;

    __shared__ char smem[2 * ASZ + 2 * BSZ];

    const int tid = threadIdx.x, lane = tid & 63, wave = tid >> 6;
    const int rl = lane & 15, kg = lane >> 4;

    const int nwg = gridDim.x;
    const int bid = blockIdx.x;
    const int bswz = (nwg & 7) ? bid : ((bid & 7) * (nwg >> 3) + (bid >> 3));
    const int row0 = bswz * MR;

    int zA[API], yxA[API], cofA[API];
    #pragma unroll
    for (int i = 0; i < API; ++i) {
        const int gi = wave * API + i;
        const int r = gi * RPI + (lane >> L2C);
        const int s = row0 + r;
        const int z = s / HWg; const int rm = s - z * HWg;
        const int y = rm / GW; const int x = rm - y * GW;
        zA[i] = z;
        yxA[i] = (y + 1) * PPW + (x + 1);
        cofA[i] = ((lane & (CPR - 1)) ^ (r & 7)) * 8;
    }
    int rB[BPI], cofB[BPI];
    #pragma unroll
    for (int i = 0; i < BPI; ++i) {
        const int gi = wave * BPI + i;
        const int r = gi * RPI + (lane >> L2C);
        rB[i] = r;
        cofB[i] = ((lane & (CPR - 1)) ^ (r & 7)) * 8;
    }

    auto stageA = [&](int bsel, int kd, int kh, int kw) {
        const int dyx = (kh - PH) * PPW + (kw - PW);
        #pragma unroll
        for (int i = 0; i < API; ++i) {
            int zp = zA[i] + (kd - PD);
            int pl = ((unsigned)zp < (unsigned)GD) ? zp : GD;
            const short* src = A + ((size_t)pl * PLP + yxA[i] + dyx) * CIN + cofA[i];
            void* dst = smem + bsel * ASZ + (wave * API + i) * 1024;
            gload16(src, dst);
        }
    };
    auto stageB = [&](int bsel, int t) {
        const short* wt = Wt + (size_t)t * 64 * CIN;
        #pragma unroll
        for (int i = 0; i < BPI; ++i) {
            const short* src = wt + rB[i] * CIN + cofB[i];
            void* dst = smem + 2 * ASZ + bsel * BSZ + (wave * BPI + i) * 1024;
            gload16(src, dst);
        }
    };

    f32x4 acc[MG][4];
    #pragma unroll
    for (int mg = 0; mg < MG; ++mg)
        #pragma unroll
        for (int ng = 0; ng < 4; ++ng)
            acc[mg][ng] = (f32x4){0.f, 0.f, 0.f, 0.f};

    auto comp = [&](int bsel) {
        const short* ab = (const short*)(smem + bsel * ASZ);
        const short* bb = (const short*)(smem + 2 * ASZ + bsel * BSZ);
        #pragma unroll
        for (int kc = 0; kc < KCN; ++kc) {
            short8 av[MG], bv[4];
            #pragma unroll
            for (int mg = 0; mg < MG; ++mg) {
                const int r = wave * (16 * MG) + mg * 16 + rl;
                const int c = (kc * 4 + kg) ^ (r & 7);
                av[mg] = *(const short8*)(ab + r * CIN + c * 8);
            }
            #pragma unroll
            for (int ng = 0; ng < 4; ++ng) {
                const int r = ng * 16 + rl;
                const int c = (kc * 4 + kg) ^ (r & 7);
                bv[ng] = *(const short8*)(bb + r * CIN + c * 8);
            }
            __builtin_amdgcn_s_setprio(1);
            #pragma unroll
            for (int mg = 0; mg < MG; ++mg)
                #pragma unroll
                for (int ng = 0; ng < 4; ++ng)
                    acc[mg][ng] = __builtin_amdgcn_mfma_f32_16x16x32_bf16(av[mg], bv[ng], acc[mg][ng], 0, 0, 0);
            __builtin_amdgcn_s_setprio(0);
        }
    };

    stageA(0, 0, 0, 0);
    stageB(0, 0);

    #pragma unroll
    for (int t = 0; t < KSZ; ++t) {
        const int cur = t & 1;
        if (t + 1 < KSZ) {
            const int t1 = t + 1;
            const int kd = t1 / (KH * KW), rm = t1 % (KH * KW);
            stageA(cur ^ 1, kd, rm / KW, rm % KW);
            stageB(cur ^ 1, t1);
            asm volatile("s_waitcnt vmcnt(%0)" :: "i"(S_IF) : "memory");
        } else {
            asm volatile("s_waitcnt vmcnt(0)" ::: "memory");
        }
        __builtin_amdgcn_s_barrier();
        __builtin_amdgcn_sched_barrier(0);
        comp(cur);
        asm volatile("s_waitcnt lgkmcnt(0)" ::: "memory");
        __builtin_amdgcn_sched_barrier(0);
        __builtin_amdgcn_s_barrier();
    }

    short (*tile)[64] = (short(*)[64])smem;
    float* red = (float*)(smem + 2 * ASZ);

    #pragma unroll
    for (int mg = 0; mg < MG; ++mg)
        #pragma unroll
        for (int ng = 0; ng < 4; ++ng)
            #pragma unroll
            for (int j = 0; j < 4; ++j) {
                float v = acc[mg][ng][j];
                if (STATS) v = (v >= 0.f) ? v : SLOPE * v;
                tile[wave * (16 * MG) + mg * 16 + kg * 4 + j][ng * 16 + rl] = f2bf(v);
            }
    __syncthreads();

    #pragma unroll
    for (int i = 0; i < MR / 32; ++i) {
        const int chunk = i * 256 + tid;
        const int r = chunk >> 3, cc = (chunk & 7) * 8;
        const int s = row0 + r;
        size_t o;
        if (OUTMODE == 0)      o = (size_t)s * 64 + cc;
        else if (OUTMODE == 1) o = (size_t)pidx_fine(s) * 64 + cc;
        else                   o = (size_t)pidx_coarse(s) * 64 + cc;
        *(short8*)(Out + o) = *(const short8*)&tile[r][cc];
    }

    if (STATS) {
        float s1 = 0.f, s2 = 0.f;
        const int col = tid & 63, rg = tid >> 6;
        #pragma unroll 4
        for (int r = rg * (MR / 4); r < (rg + 1) * (MR / 4); ++r) {
            float v = bf2f(tile[r][col]); s1 += v; s2 += v * v;
        }
        red[rg * 64 + col] = s1;
        red[256 + rg * 64 + col] = s2;
        __syncthreads();
        if (tid < 64) {
            float a = red[tid] + red[64 + tid] + red[128 + tid] + red[192 + tid];
            float b = red[256 + tid] + red[320 + tid] + red[384 + tid] + red[448 + tid];
            atomicAdd(&stats[tid], a);
            atomicAdd(&stats[64 + tid], b);
        }
    }
}

// ---------------------------------------------------------------------------
// Fine convs (C/D/E): R8-proven convmm7 + BN-fold bias accumulator (R10).
template<int KD, int KH, int PD, int PH, int OUTMODE>
__global__ __launch_bounds__(128, 1)
void convmm7(const short* __restrict__ A, const short* __restrict__ Wt,
             const float* __restrict__ bias,
             short* __restrict__ Out, float* __restrict__ stats)
{
    constexpr int KSZ = KD * KH * 3, NG = KD * KH;
    constexpr int PLP = FP_PLPTS;
    constexpr int ABYTES = 208 * 128;     // 26624
    constexpr int BBYTES = 8192;
    __shared__ __align__(16) char smem[2 * ABYTES + 2 * BBYTES];   // 69632

    const int tid = threadIdx.x, lane = tid & 63, wave = tid >> 6;  // wave 0..1
    const int rl = lane & 15, kg = lane >> 4;

    const int nwg = gridDim.x, bid = blockIdx.x;
    const int bswz = (bid & 7) * (nwg >> 3) + (bid >> 3);
    const int s0 = bswz * 192;
    const int z0 = s0 / HW1;
    const int y0 = (s0 - z0 * HW1) / 96;

    const int ptl = lane >> 3;
    const int csl = (lane & 7) ^ ptl;

    auto stageA = [&](int bsel, int g) {
        const int kd = g / KH, kh = g % KH;
        const int zp = z0 + kd - PD;
        const int pl = ((unsigned)zp < 32u) ? zp : 32;
        const int ys = y0 + kh - PH;
        const size_t base = (size_t)pl * PLP + (size_t)(ys + 1) * 98;
        #pragma unroll
        for (int i = 0; i < 13; ++i) {
            const int ii = wave * 13 + i;
            const short* src = A + (base + ii * 8 + ptl) * 64 + csl * 8;
            gload16(src, smem + bsel * ABYTES + ii * 1024);
        }
    };
    auto stageB = [&](int bsel, int t) {
        const short* wt = Wt + (size_t)t * 4096;
        #pragma unroll
        for (int i = 0; i < 4; ++i) {
            const int ii = wave * 4 + i;
            const short* src = wt + (ii * 8 + ptl) * 64 + csl * 8;
            gload16(src, smem + 2 * ABYTES + bsel * BBYTES + ii * 1024);
        }
    };

    float bc[4];
    #pragma unroll
    for (int ng = 0; ng < 4; ++ng) bc[ng] = bias[ng * 16 + rl];
    f32x4 acc[6][4];
    #pragma unroll
    for (int mg = 0; mg < 6; ++mg)
        #pragma unroll
        for (int ng = 0; ng < 4; ++ng)
            acc[mg][ng] = (f32x4){bc[ng], bc[ng], bc[ng], bc[ng]};

    const int jb = wave * 98 + rl;

    stageA(0, 0);
    stageB(0, 0);

    #pragma unroll
    for (int t = 0; t < KSZ; ++t) {
        const int g = t / 3, kw = t % 3;
        if (kw == 0 && g + 1 < NG) stageA((g + 1) & 1, g + 1);
        if (t + 1 < KSZ) stageB((t + 1) & 1, t + 1);
        if (t == KSZ - 1)
            asm volatile("s_waitcnt vmcnt(0)" ::: "memory");
        else if (kw == 0 && g + 1 < NG)
            asm volatile("s_waitcnt vmcnt(17)" ::: "memory");
        else
            asm volatile("s_waitcnt vmcnt(4)" ::: "memory");
        __builtin_amdgcn_s_barrier();
        __builtin_amdgcn_sched_barrier(0);

        const char* ab = smem + (g & 1) * ABYTES;
        const char* bb = smem + 2 * ABYTES + (t & 1) * BBYTES;
        #pragma unroll
        for (int kc = 0; kc < 2; ++kc) {
            short8 bv[4], av[6];
            #pragma unroll
            for (int ng = 0; ng < 4; ++ng) {
                const int row = ng * 16 + rl;
                bv[ng] = *(const short8*)(bb + row * 128 + (((kc * 4 + kg) ^ (rl & 7)) << 4));
            }
            #pragma unroll
            for (int mg = 0; mg < 6; ++mg) {
                const int j = jb + mg * 16 + kw;
                av[mg] = *(const short8*)(ab + j * 128 + (((kc * 4 + kg) ^ (j & 7)) << 4));
            }
            __builtin_amdgcn_s_setprio(1);
            #pragma unroll
            for (int mg = 0; mg < 6; ++mg)
                #pragma unroll
                for (int ng = 0; ng < 4; ++ng)
                    acc[mg][ng] = __builtin_amdgcn_mfma_f32_16x16x32_bf16(av[mg], bv[ng], acc[mg][ng], 0, 0, 0);
            __builtin_amdgcn_s_setprio(0);
        }
        asm volatile("s_waitcnt lgkmcnt(0)" ::: "memory");
        __builtin_amdgcn_sched_barrier(0);
        __builtin_amdgcn_s_barrier();
    }

    short (*tile)[64] = (short(*)[64])smem;
    float* red = (float*)(smem + 192 * 64 * 2);

    #pragma unroll
    for (int mg = 0; mg < 6; ++mg)
        #pragma unroll
        for (int ng = 0; ng < 4; ++ng)
            #pragma unroll
            for (int j = 0; j < 4; ++j) {
                float v = acc[mg][ng][j];
                v = (v >= 0.f) ? v : SLOPE * v;
                tile[wave * 96 + mg * 16 + kg * 4 + j][ng * 16 + rl] = f2bf(v);
            }
    __syncthreads();

    #pragma unroll
    for (int i = 0; i < 12; ++i) {
        const int chunk = i * 128 + tid;
        const int r = chunk >> 3, cc = (chunk & 7) * 8;
        const int s = s0 + r;
        size_t o;
        if (OUTMODE == 0) o = (size_t)s * 64 + cc;
        else              o = (size_t)pidx_fine(s) * 64 + cc;
        *(short8*)(Out + o) = *(const short8*)&tile[r][cc];
    }

    {
        float s1 = 0.f, s2 = 0.f;
        const int col = tid & 63, rg = tid >> 6;
        #pragma unroll 4
        for (int r = rg * 96; r < rg * 96 + 96; ++r) {
            float v = bf2f(tile[r][col]); s1 += v; s2 += v * v;
        }
        red[rg * 64 + col] = s1;
        red[128 + rg * 64 + col] = s2;
        __syncthreads();
        if (tid < 64) {
            atomicAdd(&stats[tid], red[tid] + red[64 + tid]);
            atomicAdd(&stats[64 + tid], red[128 + tid] + red[192 + tid]);
        }
    }
}

// ---------------------------------------------------------------------------
// Transposed conv by output-parity class (R6-proven) + per-class BN-fold bias.
__global__ __launch_bounds__(256, 2)
void tconv_cls(const short* __restrict__ Y, const short* __restrict__ Wt,
               const float* __restrict__ bias_up,
               const short* __restrict__ SK, short* __restrict__ Out)
{
    const int cls = blockIdx.y;
    const int pz = (cls >> 2) & 1, py = (cls >> 1) & 1, px = cls & 1;
    const int tid = threadIdx.x, lane = tid & 63, wave = tid >> 6;
    const int rl = lane & 15, kg = lane >> 4;
    const int row0 = blockIdx.x * 256;

    int zin0[4], zin1[4];
    #pragma unroll
    for (int mg = 0; mg < 4; ++mg) {
        int s = row0 + wave * 64 + mg * 16 + rl;
        int zc = s / HW0; int r = s - zc * HW0; int yc = r / W0; int xc = r - yc * W0;
        int ib = ((yc + 1) * 50 + (xc + 1)) * 64 + kg * 8;
        zin0[mg] = zc * (CP_PLPTS * 64) + ib;
        zin1[mg] = ((zc + 1 < 16) ? zc + 1 : 16) * (CP_PLPTS * 64) + ib;
    }
    const int boff = rl * 64 + kg * 8;

    float bc[4];
    #pragma unroll
    for (int ng = 0; ng < 4; ++ng) bc[ng] = bias_up[cls * 64 + ng * 16 + rl];
    f32x4 acc[4][4];
    #pragma unroll
    for (int mg = 0; mg < 4; ++mg)
        #pragma unroll
        for (int ng = 0; ng < 4; ++ng)
            acc[mg][ng] = (f32x4){bc[ng], bc[ng], bc[ng], bc[ng]};

    for (int a = 0; a <= pz; ++a) {
        const int kd = pz ? 2 * a : 1;
        for (int b = 0; b <= py; ++b) {
            const int kh = py ? 2 * b : 1;
            for (int c = 0; c <= px; ++c) {
                const int kw = px ? 2 * c : 1;
                const int t = kd * 9 + kh * 3 + kw;
                const int dlt = (b * 50 + c) * 64;
                int ao[4];
                #pragma unroll
                for (int mg = 0; mg < 4; ++mg)
                    ao[mg] = (a ? zin1[mg] : zin0[mg]) + dlt;
                #pragma unroll
                for (int kc = 0; kc < 2; ++kc) {
                    short8 av[4], bv[4];
                    #pragma unroll
                    for (int mg = 0; mg < 4; ++mg)
                        av[mg] = *(const short8*)(Y + ao[mg] + kc * 32);
                    #pragma unroll
                    for (int ng = 0; ng < 4; ++ng)
                        bv[ng] = *(const short8*)(Wt + (t * 64 + ng * 16) * 64 + boff + kc * 32);
                    #pragma unroll
                    for (int mg = 0; mg < 4; ++mg)
                        #pragma unroll
                        for (int ng = 0; ng < 4; ++ng)
                            acc[mg][ng] = __builtin_amdgcn_mfma_f32_16x16x32_bf16(av[mg], bv[ng], acc[mg][ng], 0, 0, 0);
                }
            }
        }
    }

    __shared__ short tile[256][72];
    #pragma unroll
    for (int mg = 0; mg < 4; ++mg)
        #pragma unroll
        for (int ng = 0; ng < 4; ++ng)
            #pragma unroll
            for (int j = 0; j < 4; ++j)
                tile[wave * 64 + mg * 16 + kg * 4 + j][ng * 16 + rl] = f2bf(acc[mg][ng][j]);
    __syncthreads();

    #pragma unroll
    for (int i = 0; i < 8; ++i) {
        int chunk = i * 256 + tid;
        int r = chunk >> 3, cc = (chunk & 7) * 8;
        int sl = row0 + r;
        int zc = sl / HW0; int rr = sl - zc * HW0; int yc = rr / W0; int xc = rr - yc * W0;
        int z = 2 * zc + pz, y = 2 * yc + py, x = 2 * xc + px;
        size_t so = (size_t)((z * H1 + y) * W1_ + x) * 64 + cc;
        size_t po = (size_t)(z * FP_PLPTS + (y + 1) * 98 + (x + 1)) * 64 + cc;
        short8 v = *(const short8*)&tile[r][cc];
        short8 skv = *(const short8*)(SK + so);
        short8 o;
        #pragma unroll
        for (int q = 0; q < 8; ++q) o[q] = f2bf(bf2f(v[q]) + bf2f(skv[q]));
        *(short8*)(Out + po) = o;
    }
}

// ---------------------------------------------------------------------------
extern "C" void kernel_launch(void* const* d_in, const int* in_sizes, int n_in,
                              void* d_out, int out_size, void* d_ws, size_t ws_size,
                              hipStream_t stream)
{
    const float* x       = (const float*)d_in[0];
    const float* skip    = (const float*)d_in[1];
    const float* w_trans = (const float*)d_in[2];
    const float* g_t     = (const float*)d_in[3];
    const float* b_t     = (const float*)d_in[4];
    const float* w_up    = (const float*)d_in[5];
    const float* w1      = (const float*)d_in[6];
    const float* g1      = (const float*)d_in[7];
    const float* b1      = (const float*)d_in[8];
    const float* w2      = (const float*)d_in[9];
    const float* g2      = (const float*)d_in[10];
    const float* b2      = (const float*)d_in[11];
    const float* w3      = (const float*)d_in[12];
    const float* g3      = (const float*)d_in[13];
    const float* b3      = (const float*)d_in[14];
    float* out = (float*)d_out;

    char* ws = (char*)d_ws;
    short* PadA = (short*)ws;
    short* PadB = (short*)(ws + (size_t)FP_ELEMS * 2);
    float* stats = (float*)(ws + (size_t)FP_ELEMS * 4);

    float* st0 = stats;
    float* st1 = stats + 128;
    float* st2 = stats + 256;
    float* st3 = stats + 384;
    float* bias2 = stats + 1024;
    float* bias3 = stats + 1088;
    float* bias_up = stats + 1152;   // 8*64
    float* bias_z  = stats + 1664;   // zeros (for conv C)

    char* ob = (char*)d_out;
    short* X0  = (short*)ob;
    short* Y0  = (short*)(ob + 10880000);
    short* SKb = (short*)(ob + 16320000);
    short* wt_t  = (short*)(ob + 54068736);
    short* wt_up = wt_t + 221184;
    short* wt_1  = wt_up + 110592;
    short* wt_2  = wt_1 + 36864;
    short* wt_3  = wt_2 + 36864;

    // 1. mega-prep: zero halos/trash/stats + weight repacks + both transposes
    prep0<<<NB_Z + NB_W + NB_P + NB_S, 256, 0, stream>>>(
        x, skip, w_trans, w1, PadA, PadB, X0, Y0, stats, wt_t, wt_1, SKb);

    // 2. stage A: subm 3x3x3 CIN=128 coarse -> Y0pad (raw lrelu) + stats
    convmm5<1, 128, 3, 3, 3, 1, 1, 1, 16, 48, 48, 2, true>
        <<<DHW0 / 64, 256, 0, stream>>>(X0, wt_t, Y0, st0);

    // 3. fold BN0 (fused finalize): scaled w_up + per-class bias + Y0 halo fill
    prep_up<<<432 + 512 + (T_Y + 255) / 256, 256, 0, stream>>>(
        w_up, st0, g_t, b_t, wt_up, bias_up, Y0);

    // 4. stage B: transposed conv by parity class (+bias) + skip -> PadA
    tconv_cls<<<dim3(DHW0 / 256, 8), 256, 0, stream>>>(Y0, wt_up, bias_up, SKb, PadA);

    // 5. stage C: conv (1,3,3) -> PadB raw + stats (zero bias)
    convmm7<1, 3, 0, 1, 1>
        <<<DHW1 / 192, 128, 0, stream>>>(PadA, wt_1, bias_z, PadB, st1);

    // 6. fold BN1 (fused finalize): scaled w2 + bias2 + PadB halo fill
    prep_fine<9><<<144 + 64 + (T_F + 255) / 256, 256, 0, stream>>>(
        w2, st1, g1, b1, wt_2, bias2, PadB);

    // 7. stage D: conv (3,1,3) -> PadA raw + stats
    convmm7<3, 1, 1, 0, 1>
        <<<DHW1 / 192, 128, 0, stream>>>(PadB, wt_2, bias2, PadA, st2);

    // 8. fold BN2 (fused finalize): scaled w3 + bias3 + PadA halo fill
    prep_fine<27><<<432 + 64 + (T_F + 255) / 256, 256, 0, stream>>>(
        w3, st2, g2, b2, wt_3, bias3, PadA);

    // 9. stage E: conv (3,3,3) -> PadB COMPACT raw + stats
    convmm7<3, 3, 1, 1, 0>
        <<<DHW1 / 192, 128, 0, stream>>>(PadA, wt_3, bias3, PadB, st3);

    // 10. final: BN3 (fused finalize) + transpose to NCDHW fp32
    final_out<<<DHW1 / 64, 256, 0, stream>>>(PadB, out, st3, g3, b3);
}